// Round 15
// baseline (633.079 us; speedup 1.0000x reference)
//
#include <hip/hip_runtime.h>
#include <hip/hip_bf16.h>
#include <stdint.h>

// ---------------------------------------------------------------------------
#define LSEQ 768
#define DM   256
#define NH   8
#define DK   32
#define DFF  1024
#define NLAYER 8
#define NDD  1535
// ---------------------------------------------------------------------------

typedef __attribute__((ext_vector_type(8))) short     bf16x8;
typedef __attribute__((ext_vector_type(8))) _Float16  f16x8;
typedef __attribute__((ext_vector_type(4))) float     f32x4;

__device__ __forceinline__ unsigned short f2bf(float f) {
  unsigned u = __float_as_uint(f);
  u += 0x7fffu + ((u >> 16) & 1u);       // RNE
  return (unsigned short)(u >> 16);
}
__device__ __forceinline__ unsigned short f2h(float f) {
  union { _Float16 h; unsigned short s; } c;
  c.h = (_Float16)f;                     // v_cvt_f16_f32 (RNE)
  return c.s;
}
__device__ __forceinline__ int bucket_of(int dd) {
  int rel = dd - 767;
  int ret = rel < 0 ? 32 : 0;
  int arp = rel < 0 ? -rel : rel;
  if (arp < 16) return ret + arp;
  const float lr = 2.772588722239781f;   // float(np.log(16))
  float val = logf((float)arp * 0.0625f) / lr * 16.0f;
  int vi = 16 + (int)val;
  return ret + (vi < 31 ? vi : 31);
}

// ---------------------------------------------------------------------------
// MFMA B-fragment packers: row-major [K][N] fp32 -> [K/32][N/16][lane][8] fp16
// (lane layout: n = g*16 + (lane&15), k = kc*32 + (lane>>4)*8 + e)
__device__ __forceinline__ void pack8h(unsigned short* dst, int id,
                                       const float* src, int N, int G) {
  int lane = (id >> 3) & 63;
  int rem = id >> 9;
  int g = rem % G, kc = rem / G;
  int kb = kc * 32 + ((lane >> 4) << 3);
  int n = g * 16 + (lane & 15);
  union { unsigned short s[8]; uint4 v; } U;
  #pragma unroll
  for (int e = 0; e < 8; ++e) U.s[e] = f2h(src[(size_t)(kb + e) * N + n]);
  *(uint4*)(dst + id) = U.v;
}

// N-concat of up to 3 [K][256] matrices (qkv: G=48, pair q/k: G=32)
__device__ __forceinline__ void pack8h_cat(unsigned short* dst, int id,
                                           const float* s0, const float* s1,
                                           const float* s2, int G) {
  int lane = (id >> 3) & 63;
  int rem = id >> 9;
  int g = rem % G, kc = rem / G;
  int kb = kc * 32 + ((lane >> 4) << 3);
  int n = g * 16 + (lane & 15);
  const float* sp = n < 256 ? s0 : (n < 512 ? s1 : s2);
  int nn = n & 255;
  union { unsigned short s[8]; uint4 v; } U;
  #pragma unroll
  for (int e = 0; e < 8; ++e) U.s[e] = f2h(sp[(size_t)(kb + e) * 256 + nn]);
  *(uint4*)(dst + id) = U.v;
}

// ---------------------------------------------------------------------------
// Legacy 64x64 GEMM tile (k_prep only; plain caching, gather variants).
// LDS from smc: As 2x32x68 @0, Bs @17408, stat @34816, red @35328 -> 37376.
template <int LN, int GR>
__device__ void gemm_tile(const float* gsrc, const int* seqIdx,
                          const float* B, const float* bias, float* C,
                          const float* lns, const float* lnb,
                          int M, int K, int N, int m0, int n0, char* smc) {
  float (*As)[32][68] = (float (*)[32][68])smc;
  float (*Bs)[32][68] = (float (*)[32][68])(smc + 17408);
  float (*stat)[2]    = (float (*)[2])(smc + 34816);
  float (*red)[8]     = (float (*)[8])(smc + 35328);

  int t = threadIdx.x;
  int arow = t >> 2, akq = (t & 3) * 8;
  int mg = m0 + arow;
  int mgc = mg < M ? mg : M - 1;
  const float* Ar = (GR == 1) ? (gsrc + (size_t)seqIdx[mgc] * K)
                              : (gsrc + (size_t)bucket_of(mgc) * K);
  float mean = 0.f, rstd = 0.f;
  if (LN) {
    int lq = t & 3;
    float s = 0.f, s2 = 0.f;
    const float* p = Ar + lq * 64;
    #pragma unroll
    for (int c = 0; c < 64; c += 4) {
      float4 v = *(const float4*)(p + c);
      s  += v.x + v.y + v.z + v.w;
      s2 += v.x * v.x + v.y * v.y + v.z * v.z + v.w * v.w;
    }
    red[arow][lq] = s; red[arow][lq + 4] = s2;
    __syncthreads();
    if (lq == 0) {
      float sm = red[arow][0] + red[arow][1] + red[arow][2] + red[arow][3];
      float sq = red[arow][4] + red[arow][5] + red[arow][6] + red[arow][7];
      float m = sm * (1.f / 256.f);
      float v = sq * (1.f / 256.f) - m * m;
      stat[arow][0] = m;
      stat[arow][1] = rsqrtf(v + 1e-5f);
    }
    __syncthreads();
    mean = stat[arow][0]; rstd = stat[arow][1];
  }

  int bkr = t >> 3, bn8 = (t & 7) * 8;
  int ty = t >> 4, tx = t & 15;
  float acc[4][4] = {};
  int nk = K >> 5;

  for (int kt = 0; kt < nk; ++kt) {
    int k0 = kt << 5;
    float4 a0 = *(const float4*)(Ar + k0 + akq);
    float4 a1 = *(const float4*)(Ar + k0 + akq + 4);
    if (LN) {
      float4 ls0 = *(const float4*)(lns + k0 + akq), ls1 = *(const float4*)(lns + k0 + akq + 4);
      float4 lb0 = *(const float4*)(lnb + k0 + akq), lb1 = *(const float4*)(lnb + k0 + akq + 4);
      a0.x=(a0.x-mean)*rstd*ls0.x+lb0.x; a0.y=(a0.y-mean)*rstd*ls0.y+lb0.y;
      a0.z=(a0.z-mean)*rstd*ls0.z+lb0.z; a0.w=(a0.w-mean)*rstd*ls0.w+lb0.w;
      a1.x=(a1.x-mean)*rstd*ls1.x+lb1.x; a1.y=(a1.y-mean)*rstd*ls1.y+lb1.y;
      a1.z=(a1.z-mean)*rstd*ls1.z+lb1.z; a1.w=(a1.w-mean)*rstd*ls1.w+lb1.w;
    }
    int cur = kt & 1;
    As[cur][akq+0][arow]=a0.x; As[cur][akq+1][arow]=a0.y; As[cur][akq+2][arow]=a0.z; As[cur][akq+3][arow]=a0.w;
    As[cur][akq+4][arow]=a1.x; As[cur][akq+5][arow]=a1.y; As[cur][akq+6][arow]=a1.z; As[cur][akq+7][arow]=a1.w;
    *(float4*)&Bs[cur][bkr][bn8] = *(const float4*)(B + (size_t)(k0 + bkr) * N + n0 + bn8);
    *(float4*)&Bs[cur][bkr][bn8+4] = *(const float4*)(B + (size_t)(k0 + bkr) * N + n0 + bn8 + 4);
    __syncthreads();
    #pragma unroll 8
    for (int kk = 0; kk < 32; ++kk) {
      float4 a = *(float4*)&As[cur][kk][ty * 4];
      float4 b = *(float4*)&Bs[cur][kk][tx * 4];
      acc[0][0]=fmaf(a.x,b.x,acc[0][0]); acc[0][1]=fmaf(a.x,b.y,acc[0][1]);
      acc[0][2]=fmaf(a.x,b.z,acc[0][2]); acc[0][3]=fmaf(a.x,b.w,acc[0][3]);
      acc[1][0]=fmaf(a.y,b.x,acc[1][0]); acc[1][1]=fmaf(a.y,b.y,acc[1][1]);
      acc[1][2]=fmaf(a.y,b.z,acc[1][2]); acc[1][3]=fmaf(a.y,b.w,acc[1][3]);
      acc[2][0]=fmaf(a.z,b.x,acc[2][0]); acc[2][1]=fmaf(a.z,b.y,acc[2][1]);
      acc[2][2]=fmaf(a.z,b.z,acc[2][2]); acc[2][3]=fmaf(a.z,b.w,acc[2][3]);
      acc[3][0]=fmaf(a.w,b.x,acc[3][0]); acc[3][1]=fmaf(a.w,b.y,acc[3][1]);
      acc[3][2]=fmaf(a.w,b.z,acc[3][2]); acc[3][3]=fmaf(a.w,b.w,acc[3][3]);
    }
    __syncthreads();
  }

  #pragma unroll
  for (int u = 0; u < 4; ++u) {
    int m = m0 + ty * 4 + u;
    if (m < M) {
      int n = n0 + tx * 4;
      float4 val = make_float4(acc[u][0], acc[u][1], acc[u][2], acc[u][3]);
      if (bias) {
        float4 bv = *(const float4*)(bias + n);
        val.x += bv.x; val.y += bv.y; val.z += bv.z; val.w += bv.w;
      }
      *(float4*)(C + (size_t)m * N + n) = val;
    }
  }
}

// ---------------------------------------------------------------------------
// Prep: RB gemm + qkv layer0 + embed + abias + W1p pack + fp16 weight packs.
__global__ __launch_bounds__(256, 2) void k_prep(
    const int* __restrict__ seq, const float* __restrict__ tok_emb,
    const float* __restrict__ rp_emb,
    const float* __restrict__ wq, const float* __restrict__ wk,
    const float* __restrict__ wv, const float* __restrict__ wo,
    const float* __restrict__ ffn_w1, const float* __restrict__ ffn_w2,
    const float* __restrict__ ln1s0, const float* __restrict__ ln1b0,
    const float* __restrict__ pair_rp, const float* __restrict__ cls_w1,
    const float* __restrict__ cls_b1,
    const float* __restrict__ pair_q_w, const float* __restrict__ pair_k_w,
    float* x0, float* q0, float* k0, float* v0, float* RB,
    unsigned short* W1p, float* abias,
    unsigned short* Wop, unsigned short* W1pk, unsigned short* W2pk,
    unsigned short* Wqkvp, unsigned short* Wpairp) {
  __shared__ __align__(16) char sm[37376];
  int b = blockIdx.x, t = threadIdx.x;
  if (b < 96) {
    int m0 = (b % 24) * 64, n0 = (b / 24) * 64;
    gemm_tile<0,2>(pair_rp, nullptr, cls_w1, cls_b1, RB,
                   nullptr, nullptr, NDD, 256, 256, m0, n0, sm);
  } else if (b < 240) {
    int u = b - 96;
    int n0g = (u % 12) * 64, m0 = (u / 12) * 64;
    int bi = n0g >> 8, n0 = n0g & 255;
    const float* B = bi == 0 ? wq : (bi == 1 ? wk : wv);
    float* C = bi == 0 ? q0 : (bi == 1 ? k0 : v0);
    gemm_tile<1,1>(tok_emb, seq, B, nullptr, C,
                   ln1s0, ln1b0, LSEQ, 256, 256, m0, n0, sm);
  } else if (b < 432) {
    int row = (b - 240) * 4 + (t >> 6), c = (t & 63) * 4;
    *(float4*)(x0 + (size_t)row * DM + c) =
        *(const float4*)(tok_emb + (size_t)seq[row] * DM + c);
  } else if (b < 438) {
    int dd = (b - 432) * 256 + t;
    if (dd < NDD) {
      int bk = bucket_of(dd);
      #pragma unroll
      for (int h = 0; h < NH; ++h) abias[dd * 8 + h] = rp_emb[bk * 8 + h];
    }
  } else if (b < 502) {
    // cls_w1 pack -> fp16 fragments (consumed by k_pair3)
    int base = (b - 438) * 1024 + t * 4;
    #pragma unroll
    for (int uu = 0; uu < 4; ++uu) {
      int id = base + uu;
      int e = id & 7, lane = (id >> 3) & 63, g = (id >> 9) & 15, kc = id >> 13;
      int kg = kc * 32 + (lane >> 4) * 8 + e;
      int n  = g * 16 + (lane & 15);
      W1p[id] = f2h(cls_w1[(size_t)kg * 256 + n]);
    }
  } else {
    // fp16 MFMA weight packing: 3136 blocks x 2048 elems
    int u = (b - 502) * 2048 + t * 8;
    if (u < 524288) {                       // wo: 8 x [256][256], G=16
      int layer = u >> 16, id = u & 65535;
      pack8h(Wop + ((size_t)layer << 16), id, wo + ((size_t)layer << 16), 256, 16);
    } else if (u < 2621440) {               // ffn_w1: 8 x [256][1024], G=64
      int v2 = u - 524288; int layer = v2 >> 18, id = v2 & 262143;
      pack8h(W1pk + ((size_t)layer << 18), id, ffn_w1 + ((size_t)layer << 18), 1024, 64);
    } else if (u < 4718592) {               // ffn_w2: 8 x [1024][256], G=16
      int v2 = u - 2621440; int layer = v2 >> 18, id = v2 & 262143;
      pack8h(W2pk + ((size_t)layer << 18), id, ffn_w2 + ((size_t)layer << 18), 256, 16);
    } else if (u < 6291456) {               // qkv concat: 8 x [256][768], G=48
      int v2 = u - 4718592; int layer = v2 / 196608, id = v2 - layer * 196608;
      pack8h_cat(Wqkvp + (size_t)layer * 196608, id,
                 wq + ((size_t)layer << 16), wk + ((size_t)layer << 16),
                 wv + ((size_t)layer << 16), 48);
    } else {                                // pair q/k concat: [256][512], G=32
      int id = u - 6291456;
      pack8h_cat(Wpairp, id, pair_q_w, pair_k_w, pair_k_w, 32);
    }
  }
}

// ---------------------------------------------------------------------------
// Attention (validated round 7): 16 q-rows x 1 head per block.
#define ATTN_SMEM 72960

__global__ __launch_bounds__(256, 2) void k_attn2(
    const float* __restrict__ q, const float* __restrict__ k,
    const float* __restrict__ v, const float* __restrict__ abias,
    float* __restrict__ o) {
  extern __shared__ char sm[];
  float* S  = (float*)sm;
  float* KV = (float*)(sm + 49664);
  float* QS = (float*)(sm + 66560);
  float* BS = (float*)(sm + 68672);
  float (*red)[16] = (float (*)[16])(sm + 71808);
  float* mrow = (float*)(sm + 72832);
  float* linv = (float*)(sm + 72896);

  int i0 = blockIdx.x * 16, h = blockIdx.y, hc = h * DK;
  int t = threadIdx.x;

  for (int u = t; u < 783; u += 256)
    BS[u] = abias[(size_t)(i0 + u) * 8 + h];
  {
    int r = t >> 4, c = t & 15;
    const float inv = 0.17677669529663687f;   // 1/sqrt(32)
    QS[r * 33 + c]      = q[(size_t)(i0 + r) * DM + hc + c] * inv;
    QS[r * 33 + c + 16] = q[(size_t)(i0 + r) * DM + hc + c + 16] * inv;
  }

  int kx = t & 31, ry = t >> 5;
  int key = t >> 1, half = t & 1;

  for (int cc = 0; cc < 6; ++cc) {
    const float* kp = k + (size_t)(cc * 128 + key) * DM + hc + half * 16;
    float4 L0 = *(const float4*)(kp);
    float4 L1 = *(const float4*)(kp + 4);
    float4 L2 = *(const float4*)(kp + 8);
    float4 L3 = *(const float4*)(kp + 12);
    __syncthreads();
    int cb = half * 16;
    KV[(cb+ 0)*132+key]=L0.x; KV[(cb+ 1)*132+key]=L0.y; KV[(cb+ 2)*132+key]=L0.z; KV[(cb+ 3)*132+key]=L0.w;
    KV[(cb+ 4)*132+key]=L1.x; KV[(cb+ 5)*132+key]=L1.y; KV[(cb+ 6)*132+key]=L1.z; KV[(cb+ 7)*132+key]=L1.w;
    KV[(cb+ 8)*132+key]=L2.x; KV[(cb+ 9)*132+key]=L2.y; KV[(cb+10)*132+key]=L2.z; KV[(cb+11)*132+key]=L2.w;
    KV[(cb+12)*132+key]=L3.x; KV[(cb+13)*132+key]=L3.y; KV[(cb+14)*132+key]=L3.z; KV[(cb+15)*132+key]=L3.w;
    __syncthreads();

    float s0x=0,s0y=0,s0z=0,s0w=0, s1x=0,s1y=0,s1z=0,s1w=0;
    #pragma unroll
    for (int kk = 0; kk < 32; ++kk) {
      float q0 = QS[(ry*2    )*33 + kk];
      float q1 = QS[(ry*2 + 1)*33 + kk];
      float4 kv4 = *(const float4*)&KV[kk*132 + kx*4];
      s0x = fmaf(q0, kv4.x, s0x); s0y = fmaf(q0, kv4.y, s0y);
      s0z = fmaf(q0, kv4.z, s0z); s0w = fmaf(q0, kv4.w, s0w);
      s1x = fmaf(q1, kv4.x, s1x); s1y = fmaf(q1, kv4.y, s1y);
      s1z = fmaf(q1, kv4.z, s1z); s1w = fmaf(q1, kv4.w, s1w);
    }
    int jb = cc * 128 + kx * 4;
    int r0 = ry * 2, r1 = r0 + 1;
    S[r0*776 + jb+0] = s0x + BS[r0 + 767 - (jb+0)];
    S[r0*776 + jb+1] = s0y + BS[r0 + 767 - (jb+1)];
    S[r0*776 + jb+2] = s0z + BS[r0 + 767 - (jb+2)];
    S[r0*776 + jb+3] = s0w + BS[r0 + 767 - (jb+3)];
    S[r1*776 + jb+0] = s1x + BS[r1 + 767 - (jb+0)];
    S[r1*776 + jb+1] = s1y + BS[r1 + 767 - (jb+1)];
    S[r1*776 + jb+2] = s1z + BS[r1 + 767 - (jb+2)];
    S[r1*776 + jb+3] = s1w + BS[r1 + 767 - (jb+3)];
  }
  __syncthreads();

  {
    int ti = t >> 4, tj = t & 15;
    float mx = -1e30f;
    for (int jc = 0; jc < 48; ++jc)
      mx = fmaxf(mx, S[ti*776 + jc*16 + tj]);
    red[ti][tj] = mx;
    __syncthreads();
    if (tj == 0) {
      float m2 = red[ti][0];
      #pragma unroll
      for (int u = 1; u < 16; ++u) m2 = fmaxf(m2, red[ti][u]);
      mrow[ti] = m2;
    }
    __syncthreads();
    float m2 = mrow[ti];
    float sum = 0.f;
    for (int jc = 0; jc < 48; ++jc) {
      int j = jc*16 + tj;
      float e = __expf(S[ti*776 + j] - m2);
      S[ti*776 + j] = e;
      sum += e;
    }
    red[ti][tj] = sum;
    __syncthreads();
    if (tj == 0) {
      float s2 = 0.f;
      #pragma unroll
      for (int u = 0; u < 16; ++u) s2 += red[ti][u];
      linv[ti] = 1.f / s2;
    }
  }

  int cp = t & 15, jg = t >> 4;
  int c0 = cp * 2, c1 = c0 + 1;
  float oc0[16] = {}, oc1[16] = {};
  for (int cc = 0; cc < 6; ++cc) {
    const float* vp = v + (size_t)(cc * 128 + key) * DM + hc + half * 16;
    float4 L0 = *(const float4*)(vp);
    float4 L1 = *(const float4*)(vp + 4);
    float4 L2 = *(const float4*)(vp + 8);
    float4 L3 = *(const float4*)(vp + 12);
    __syncthreads();
    int cb = half * 16;
    KV[(cb+ 0)*132+key]=L0.x; KV[(cb+ 1)*132+key]=L0.y; KV[(cb+ 2)*132+key]=L0.z; KV[(cb+ 3)*132+key]=L0.w;
    KV[(cb+ 4)*132+key]=L1.x; KV[(cb+ 5)*132+key]=L1.y; KV[(cb+ 6)*132+key]=L1.z; KV[(cb+ 7)*132+key]=L1.w;
    KV[(cb+ 8)*132+key]=L2.x; KV[(cb+ 9)*132+key]=L2.y; KV[(cb+10)*132+key]=L2.z; KV[(cb+11)*132+key]=L2.w;
    KV[(cb+12)*132+key]=L3.x; KV[(cb+13)*132+key]=L3.y; KV[(cb+14)*132+key]=L3.z; KV[(cb+15)*132+key]=L3.w;
    __syncthreads();

    #pragma unroll
    for (int jj2 = 0; jj2 < 2; ++jj2) {
      int jb = jg * 8 + jj2 * 4;
      float4 vA = *(const float4*)&KV[c0*132 + jb];
      float4 vB = *(const float4*)&KV[c1*132 + jb];
      #pragma unroll
      for (int r = 0; r < 16; ++r) {
        float4 sv = *(const float4*)&S[r*776 + cc*128 + jb];
        oc0[r] += sv.x*vA.x + sv.y*vA.y + sv.z*vA.z + sv.w*vA.w;
        oc1[r] += sv.x*vB.x + sv.y*vB.y + sv.z*vB.z + sv.w*vB.w;
      }
    }
  }

  #pragma unroll
  for (int h2 = 0; h2 < 2; ++h2) {
    __syncthreads();
    #pragma unroll
    for (int r = 0; r < 8; ++r) {
      KV[(jg*8 + r)*32 + c0] = oc0[h2*8 + r];
      KV[(jg*8 + r)*32 + c1] = oc1[h2*8 + r];
    }
    __syncthreads();
    int r = t >> 5, c = t & 31;
    float s = 0.f;
    #pragma unroll
    for (int jgg = 0; jgg < 16; ++jgg) s += KV[(jgg*8 + r)*32 + c];
    o[(size_t)(i0 + h2*8 + r) * DM + hc + c] = s * linv[h2*8 + r];
  }
}

// ---------------------------------------------------------------------------
// Layer tail, wave-maximized (validated round 7): 1 16x16 MFMA tile per wave.

// k_wo: X1 = xin + O@Wo. grid (48,4) x 256thr; wave w -> g = by*4+w.
__global__ __launch_bounds__(256, 2) void k_wo(
    const float* __restrict__ o, const float* __restrict__ xin,
    const unsigned short* __restrict__ wop, float* __restrict__ x1) {
  __shared__ __align__(16) _Float16 Ab[16][264];
  int t = threadIdx.x;
  int i0 = blockIdx.x * 16;
  int by = blockIdx.y;
  int w = t >> 6, l = t & 63;
  int lr = l & 15, lq = l >> 4;

  {
    int r = t >> 4, j = t & 15;
    #pragma unroll
    for (int q = 0; q < 4; ++q) {
      int c = j * 4 + q * 64;
      float4 v = *(const float4*)(o + (size_t)(i0 + r) * DM + c);
      union { _Float16 h[4]; uint2 u; } cv;
      cv.h[0] = (_Float16)v.x; cv.h[1] = (_Float16)v.y;
      cv.h[2] = (_Float16)v.z; cv.h[3] = (_Float16)v.w;
      *(uint2*)&Ab[r][c] = cv.u;
    }
  }
  __syncthreads();

  f16x8 af[8];
  #pragma unroll
  for (int kc = 0; kc < 8; ++kc)
    af[kc] = *(const f16x8*)&Ab[lr][kc * 32 + lq * 8];

  int g = by * 4 + w;
  const unsigned short* wp = wop + (size_t)l * 8;
  f32x4 ac = {0.f, 0.f, 0.f, 0.f};
  #pragma unroll
  for (int kc = 0; kc < 8; ++kc) {
    f16x8 bb = *(const f16x8*)(wp + ((kc * 16 + g) << 9));
    ac = __builtin_amdgcn_mfma_f32_16x16x32_f16(af[kc], bb, ac, 0, 0, 0);
  }
  int n = g * 16 + lr;
  #pragma unroll
  for (int r = 0; r < 4; ++r) {
    int row = i0 + lq * 4 + r;
    x1[(size_t)row * DM + n] = xin[(size_t)row * DM + n] + ac[r];
  }
}

// k_ffn1: LN2(x1) -> ffn1 chunk + gelu -> Fg. grid (48,16); wave -> g = by*4+w.
__global__ __launch_bounds__(256, 2) void k_ffn1(
    const float* __restrict__ x1,
    const float* __restrict__ ln2s, const float* __restrict__ ln2b,
    const unsigned short* __restrict__ w1p, const float* __restrict__ fb1,
    unsigned short* __restrict__ Fg) {
  __shared__ __align__(16) _Float16 Ab[16][264];
  int t = threadIdx.x;
  int i0 = blockIdx.x * 16;
  int by = blockIdx.y;
  int w = t >> 6, l = t & 63;
  int lr = l & 15, lq = l >> 4;

  // LN2 from global x1 (16 threads/row, shuffle reduce) -> Ab fp16
  {
    int r = t >> 4, j = t & 15;
    int c0 = j * 16;
    const float* xp = x1 + (size_t)(i0 + r) * DM + c0;
    float xv[16]; float s1 = 0.f, s2 = 0.f;
    #pragma unroll
    for (int u = 0; u < 16; u += 4) {
      float4 v = *(const float4*)(xp + u);
      xv[u] = v.x; xv[u+1] = v.y; xv[u+2] = v.z; xv[u+3] = v.w;
      s1 += v.x + v.y + v.z + v.w;
      s2 += v.x*v.x + v.y*v.y + v.z*v.z + v.w*v.w;
    }
    #pragma unroll
    for (int m = 1; m < 16; m <<= 1) {
      s1 += __shfl_xor(s1, m);
      s2 += __shfl_xor(s2, m);
    }
    float mean = s1 * (1.f / 256.f);
    float var  = s2 * (1.f / 256.f) - mean * mean;
    float rs = rsqrtf(var + 1e-5f);
    #pragma unroll
    for (int p = 0; p < 4; ++p) {
      union { _Float16 h[4]; uint2 u; } cv;
      #pragma unroll
      for (int e = 0; e < 4; ++e) {
        int c = c0 + p * 4 + e;
        cv.h[e] = (_Float16)((xv[p * 4 + e] - mean) * rs * ln2s[c] + ln2b[c]);
      }
      *(uint2*)&Ab[r][c0 + p * 4] = cv.u;
    }
  }
  __syncthreads();

  f16x8 af[8];
  #pragma unroll
  for (int kc = 0; kc < 8; ++kc)
    af[kc] = *(const f16x8*)&Ab[lr][kc * 32 + lq * 8];

  int g = by * 4 + w;
  const unsigned short* wp = w1p + (size_t)l * 8;
  f32x4 ac = {0.f, 0.f, 0.f, 0.f};
  #pragma unroll
  for (int kc = 0; kc < 8; ++kc) {
    f16x8 bb = *(const f16x8*)(wp + ((kc * 64 + g) << 9));
    ac = __builtin_amdgcn_mfma_f32_16x16x32_f16(af[kc], bb, ac, 0, 0, 0);
  }
  int n = g * 16 + lr;
  float b1 = fb1[n];
  #pragma unroll
  for (int r = 0; r < 4; ++r) {
    float v = ac[r] + b1;
    v = 0.5f * v * (1.f + erff(v * 0.70710678118654752f));
    Fg[(size_t)(i0 + lq * 4 + r) * DFF + n] = f2h(v);
  }
}

// k_ffn2: X2 = X1 + F@W2 + b2. grid (48,16); block = one 16x16 tile (g = by),
// 4 waves K-split K=1024 (256 each), LDS partial reduce, wave 0 writes.
__global__ __launch_bounds__(256, 2) void k_ffn2(
    const unsigned short* __restrict__ Fg, const float* __restrict__ x1,
    const unsigned short* __restrict__ w2p, const float* __restrict__ fb2,
    float* __restrict__ x2) {
  __shared__ __align__(16) _Float16 Fs[16][1032];
  __shared__ float part[3][16][17];
  int t = threadIdx.x;
  int i0 = blockIdx.x * 16;
  int g = blockIdx.y;
  int w = t >> 6, l = t & 63;
  int lr = l & 15, lq = l >> 4;

  {
    int r = t >> 4, j = t & 15;
    #pragma unroll
    for (int q = 0; q < 8; ++q) {
      int c = j * 8 + q * 128;
      *(uint4*)&Fs[r][c] = *(const uint4*)(Fg + (size_t)(i0 + r) * DFF + c);
    }
  }
  __syncthreads();

  const unsigned short* wp = w2p + (size_t)l * 8;
  f32x4 ac = {0.f, 0.f, 0.f, 0.f};
  #pragma unroll
  for (int k8 = 0; k8 < 8; ++k8) {
    int kc = w * 8 + k8;
    f16x8 fa = *(const f16x8*)&Fs[lr][kc * 32 + lq * 8];
    f16x8 bb = *(const f16x8*)(wp + ((kc * 16 + g) << 9));
    ac = __builtin_amdgcn_mfma_f32_16x16x32_f16(fa, bb, ac, 0, 0, 0);
  }
  if (w > 0) {
    #pragma unroll
    for (int r = 0; r < 4; ++r)
      part[w - 1][lq * 4 + r][lr] = ac[r];
  }
  __syncthreads();
  if (w == 0) {
    int n = g * 16 + lr;
    float b2v = fb2[n];
    #pragma unroll
    for (int r = 0; r < 4; ++r) {
      int rr = lq * 4 + r;
      int row = i0 + rr;
      float s = ac[r] + part[0][rr][lr] + part[1][rr][lr] + part[2][rr][lr];
      x2[(size_t)row * DM + n] = x1[(size_t)row * DM + n] + s + b2v;
    }
  }
}

// k_t3: LN1next/LNf + qkv chunk (or pair projection). 1 g per wave.
// grid (48,12) for qkv (G=48), (48,8) for pair (G=32).
template <int LAST>
__global__ __launch_bounds__(256, 2) void k_t3(
    const float* __restrict__ x2,
    const float* __restrict__ lns, const float* __restrict__ lnb,
    const unsigned short* __restrict__ wnp,
    const float* __restrict__ nb0, const float* __restrict__ nb1,
    float* __restrict__ qo, float* __restrict__ ko, float* __restrict__ vo) {
  __shared__ __align__(16) _Float16 Ab[16][264];
  int t = threadIdx.x;
  int i0 = blockIdx.x * 16;
  int by = blockIdx.y;
  int w = t >> 6, l = t & 63;
  int lr = l & 15, lq = l >> 4;

  {
    int r = t >> 4, j = t & 15;
    int c0 = j * 16;
    const float* xp = x2 + (size_t)(i0 + r) * DM + c0;
    float xv[16]; float s1 = 0.f, s2 = 0.f;
    #pragma unroll
    for (int u = 0; u < 16; u += 4) {
      float4 v = *(const float4*)(xp + u);
      xv[u] = v.x; xv[u+1] = v.y; xv[u+2] = v.z; xv[u+3] = v.w;
      s1 += v.x + v.y + v.z + v.w;
      s2 += v.x*v.x + v.y*v.y + v.z*v.z + v.w*v.w;
    }
    #pragma unroll
    for (int m = 1; m < 16; m <<= 1) {
      s1 += __shfl_xor(s1, m);
      s2 += __shfl_xor(s2, m);
    }
    float mean = s1 * (1.f / 256.f);
    float var  = s2 * (1.f / 256.f) - mean * mean;
    float rs = rsqrtf(var + 1e-5f);
    #pragma unroll
    for (int p = 0; p < 4; ++p) {
      union { _Float16 h[4]; uint2 u; } cv;
      #pragma unroll
      for (int e = 0; e < 4; ++e) {
        int c = c0 + p * 4 + e;
        cv.h[e] = (_Float16)((xv[p * 4 + e] - mean) * rs * lns[c] + lnb[c]);
      }
      *(uint2*)&Ab[r][c0 + p * 4] = cv.u;
    }
  }
  __syncthreads();

  f16x8 af[8];
  #pragma unroll
  for (int kc = 0; kc < 8; ++kc)
    af[kc] = *(const f16x8*)&Ab[lr][kc * 32 + lq * 8];

  const unsigned short* wp = wnp + (size_t)l * 8;
  int g = by * 4 + w;
  if (!LAST) {
    f32x4 ac = {0.f, 0.f, 0.f, 0.f};
    #pragma unroll
    for (int kc = 0; kc < 8; ++kc) {
      f16x8 bb = *(const f16x8*)(wp + ((kc * 48 + g) << 9));
      ac = __builtin_amdgcn_mfma_f32_16x16x32_f16(af[kc], bb, ac, 0, 0, 0);
    }
    int n = g * 16 + lr;
    float* dst = n < 256 ? qo : (n < 512 ? ko : vo);
    int nn = n & 255;
    #pragma unroll
    for (int r = 0; r < 4; ++r)
      dst[(size_t)(i0 + lq * 4 + r) * DM + nn] = ac[r];
  } else {
    f32x4 ac = {0.f, 0.f, 0.f, 0.f};
    #pragma unroll
    for (int kc = 0; kc < 8; ++kc) {
      f16x8 bb = *(const f16x8*)(wp + ((kc * 32 + g) << 9));
      ac = __builtin_amdgcn_mfma_f32_16x16x32_f16(af[kc], bb, ac, 0, 0, 0);
    }
    int n = g * 16 + lr;
    float* dst = n < 256 ? qo : ko;
    const float* bias = n < 256 ? nb0 : nb1;
    int nn = n & 255;
    float bv = bias[nn];
    #pragma unroll
    for (int r = 0; r < 4; ++r)
      dst[(size_t)(i0 + lq * 4 + r) * DM + nn] = ac[r] + bv;
  }
}

// ---------------------------------------------------------------------------
// Fused pair head v7: r12 core, but each wave owns a DISJOINT 64-col n-slice
// (w = n-slice id; 4 nt frags/wave) and computes all 4 q-rows x both j-halves
// (af[8], acc[8][4]). Halves W1p L2 traffic (no duplicate reads across wave
// pairs) and halves per-kc load count while MFMA/kc stays 32. Epilogue:
// disjoint stores racc2[4][128][2] + 4-way final add.
__global__ __launch_bounds__(256, 2) void k_pair3(
    const float* __restrict__ pq, const float* __restrict__ pk,
    const unsigned short* __restrict__ W1p, const float* __restrict__ RB,
    const float* __restrict__ w2, const float* __restrict__ b2,
    float* __restrict__ out) {
  __shared__ __align__(16) _Float16 qsh[4][264];
  __shared__ __align__(16) _Float16 ksh[32][264];
  __shared__ __align__(16) float    RB_s[35][260];
  __shared__ float racc2[4][128][2];

  int t = threadIdx.x;
  int j0 = blockIdx.x * 32;
  int i0 = blockIdx.y * 4;
  int w = t >> 6, l = t & 63;
  int q4 = l >> 4, l15 = l & 15;

  // stage q (4x256) + k (32x256) as fp16, RB tile as fp32
  {
    if (t < 128) {
      int kr = t >> 5, c8 = (t & 31) * 8;
      const float* sp = pq + (size_t)(i0 + kr) * DM + c8;
      float4 a = *(const float4*)sp, b = *(const float4*)(sp + 4);
      f16x8 h;
      h[0]=(_Float16)a.x; h[1]=(_Float16)a.y; h[2]=(_Float16)a.z; h[3]=(_Float16)a.w;
      h[4]=(_Float16)b.x; h[5]=(_Float16)b.y; h[6]=(_Float16)b.z; h[7]=(_Float16)b.w;
      *(f16x8*)&qsh[kr][c8] = h;
    }
    #pragma unroll
    for (int r8 = 0; r8 < 4; ++r8) {
      int idx = t + r8 * 256;
      int kr = idx >> 5, c8 = (idx & 31) * 8;
      const float* sp = pk + (size_t)(j0 + kr) * DM + c8;
      float4 a = *(const float4*)sp, b = *(const float4*)(sp + 4);
      f16x8 h;
      h[0]=(_Float16)a.x; h[1]=(_Float16)a.y; h[2]=(_Float16)a.z; h[3]=(_Float16)a.w;
      h[4]=(_Float16)b.x; h[5]=(_Float16)b.y; h[6]=(_Float16)b.z; h[7]=(_Float16)b.w;
      *(f16x8*)&ksh[kr][c8] = h;
    }
    int ddmin = i0 - j0 + 736;
    for (int idx = t; idx < 35 * 64; idx += 256) {
      int lc = idx >> 6, c4b = (idx & 63) * 4;
      *(float4*)&RB_s[lc][c4b] =
          *(const float4*)(RB + (size_t)(ddmin + lc) * 256 + c4b);
    }
  }
  __syncthreads();

  // wave w owns n-slice [w*64, w*64+63]: g = w*4 + nt
  const unsigned short* Bp = W1p + (size_t)(w * 4) * 512 + (size_t)l * 8;

  f32x4 acc[8][4];
  #pragma unroll
  for (int aa = 0; aa < 8; ++aa)
    #pragma unroll
    for (int bb = 0; bb < 4; ++bb) acc[aa][bb] = (f32x4){0.f, 0.f, 0.f, 0.f};

  f16x8 bcur[4];
  #pragma unroll
  for (int nt = 0; nt < 4; ++nt) bcur[nt] = *(const f16x8*)(Bp + nt * 512);

  for (int kc = 0; kc < 8; ++kc) {
    f16x8 bnxt[4];
    if (kc < 7) {
      const unsigned short* bbn = Bp + (size_t)(kc + 1) * 8192;
      #pragma unroll
      for (int nt = 0; nt < 4; ++nt) bnxt[nt] = *(const f16x8*)(bbn + nt * 512);
    }
    int c = kc * 32 + q4 * 8;
    f16x8 ka = *(const f16x8*)&ksh[l15][c];
    f16x8 kb = *(const f16x8*)&ksh[16 + l15][c];
    f16x8 q0 = *(const f16x8*)&qsh[0][c];
    f16x8 q1 = *(const f16x8*)&qsh[1][c];
    f16x8 q2 = *(const f16x8*)&qsh[2][c];
    f16x8 q3 = *(const f16x8*)&qsh[3][c];

    f16x8 af0 = q0 * ka, af1 = q0 * kb;
    f16x8 af2 = q1 * ka, af3 = q1 * kb;
    f16x8 af4 = q2 * ka, af5 = q2 * kb;
    f16x8 af6 = q3 * ka, af7 = q3 * kb;

    #pragma unroll
    for (int nt = 0; nt < 4; ++nt) {
      acc[0][nt] = __builtin_amdgcn_mfma_f32_16x16x32_f16(af0, bcur[nt], acc[0][nt], 0, 0, 0);
      acc[1][nt] = __builtin_amdgcn_mfma_f32_16x16x32_f16(af1, bcur[nt], acc[1][nt], 0, 0, 0);
      acc[2][nt] = __builtin_amdgcn_mfma_f32_16x16x32_f16(af2, bcur[nt], acc[2][nt], 0, 0, 0);
      acc[3][nt] = __builtin_amdgcn_mfma_f32_16x16x32_f16(af3, bcur[nt], acc[3][nt], 0, 0, 0);
      acc[4][nt] = __builtin_amdgcn_mfma_f32_16x16x32_f16(af4, bcur[nt], acc[4][nt], 0, 0, 0);
      acc[5][nt] = __builtin_amdgcn_mfma_f32_16x16x32_f16(af5, bcur[nt], acc[5][nt], 0, 0, 0);
      acc[6][nt] = __builtin_amdgcn_mfma_f32_16x16x32_f16(af6, bcur[nt], acc[6][nt], 0, 0, 0);
      acc[7][nt] = __builtin_amdgcn_mfma_f32_16x16x32_f16(af7, bcur[nt], acc[7][nt], 0, 0, 0);
    }
    if (kc < 7) {
      #pragma unroll
      for (int nt = 0; nt < 4; ++nt) bcur[nt] = bnxt[nt];
    }
  }

  float w20[4], w21[4];
  #pragma unroll
  for (int nt = 0; nt < 4; ++nt) {
    int n = w * 64 + nt * 16 + l15;
    w20[nt] = w2[n * 2];
    w21[nt] = w2[n * 2 + 1];
  }
  #pragma unroll
  for (int mt = 0; mt < 8; ++mt) {
    #pragma unroll
    for (int reg = 0; reg < 4; ++reg) {
      int r = mt * 16 + q4 * 4 + reg;     // r = 32*qr + 16*jh + jw
      int lc = (r >> 5) - (r & 31) + 31;
      float o0 = 0.f, o1 = 0.f;
      #pragma unroll
      for (int nt = 0; nt < 4; ++nt) {
        int n = w * 64 + nt * 16 + l15;
        float T = acc[mt][nt][reg] + RB_s[lc][n];
        T = fmaxf(T, 0.f);
        o0 = fmaf(T, w20[nt], o0);
        o1 = fmaf(T, w21[nt], o1);
      }
      #pragma unroll
      for (int s = 1; s < 16; s <<= 1) {
        o0 += __shfl_xor(o0, s);
        o1 += __shfl_xor(o1, s);
      }
      if (l15 == 0) {
        racc2[w][r][0] = o0;
        racc2[w][r][1] = o1;
      }
    }
  }
  __syncthreads();
  {
    int r = t >> 1, oo = t & 1;
    out[((size_t)(i0 + (r >> 5)) * LSEQ + (j0 + (r & 31))) * 2 + oo] =
        racc2[0][r][oo] + racc2[1][r][oo] + racc2[2][r][oo] + racc2[3][r][oo] +
        b2[oo];
  }
}

// ---------------------------------------------------------------------------
extern "C" void kernel_launch(void* const* d_in, const int* in_sizes, int n_in,
                              void* d_out, int out_size, void* d_ws, size_t ws_size,
                              hipStream_t stream) {
  const int*   seq      = (const int*)  d_in[0];
  const float* tok_emb  = (const float*)d_in[1];
  const float* rp_emb   = (const float*)d_in[2];
  const float* wq       = (const float*)d_in[3];
  const float* wk       = (const float*)d_in[4];
  const float* wv       = (const float*)d_in[5];
  const float* wo       = (const float*)d_in[6];
  const float* ln1_s    = (const float*)d_in[7];
  const float* ln1_b    = (const float*)d_in[8];
  const float* ln2_s    = (const float*)d_in[9];
  const float* ln2_b    = (const float*)d_in[10];
  const float* ffn_w1   = (const float*)d_in[11];
  const float* ffn_b1   = (const float*)d_in[12];
  const float* ffn_w2   = (const float*)d_in[13];
  const float* ffn_b2   = (const float*)d_in[14];
  const float* lnf_s    = (const float*)d_in[15];
  const float* lnf_b    = (const float*)d_in[16];
  const float* pair_q_w = (const float*)d_in[17];
  const float* pair_q_b = (const float*)d_in[18];
  const float* pair_k_w = (const float*)d_in[19];
  const float* pair_k_b = (const float*)d_in[20];
  const float* pair_rp  = (const float*)d_in[21];
  const float* cls_w1   = (const float*)d_in[22];
  const float* cls_b1   = (const float*)d_in[23];
  const float* cls_w2   = (const float*)d_in[24];
  const float* cls_b2   = (const float*)d_in[25];
  float* out = (float*)d_out;

  char* ws = (char*)d_ws;
  float* xb0 = (float*)(ws + 0);
  float* xb1 = (float*)(ws + 786432);
  float* qb[2] = { (float*)(ws + 1572864), (float*)(ws + 3932160) };
  float* kb[2] = { (float*)(ws + 2359296), (float*)(ws + 4718592) };
  float* vb[2] = { (float*)(ws + 3145728), (float*)(ws + 5505024) };
  float* o   = (float*)(ws + 6291456);
  float* pq  = (float*)(ws + 7077888);
  float* pk  = (float*)(ws + 7864320);
  float* RB  = (float*)(ws + 8650752);
  unsigned short* W1p = (unsigned short*)(ws + 10223616);
  float* abias = (float*)(ws + 10354688);
  // packed fp16 MFMA weights
  unsigned short* Wop    = (unsigned short*)(ws + 10403840);  // 8 x 65536  x2B
  unsigned short* W1pk   = (unsigned short*)(ws + 11452416);  // 8 x 262144 x2B
  unsigned short* W2pk   = (unsigned short*)(ws + 15646720);  // 8 x 262144 x2B
  unsigned short* Wqkvp  = (unsigned short*)(ws + 19841024);  // 8 x 196608 x2B
  unsigned short* Wpairp = (unsigned short*)(ws + 22986752);  // 131072 x2B
  unsigned short* Fg     = (unsigned short*)(ws + 23248896);  // 768x1024 fp16
  float* x1buf           = (float*)(ws + 24821760);           // 768x256 f32

  (void)in_sizes; (void)n_in; (void)out_size; (void)ws_size;

  hipFuncSetAttribute(reinterpret_cast<const void*>(k_attn2),
                      hipFuncAttributeMaxDynamicSharedMemorySize, ATTN_SMEM);

  k_prep<<<3638, 256, 0, stream>>>(seq, tok_emb, rp_emb, wq, wk, wv, wo,
                                   ffn_w1, ffn_w2, ln1_s, ln1_b,
                                   pair_rp, cls_w1, cls_b1, pair_q_w, pair_k_w,
                                   xb0, qb[0], kb[0], vb[0], RB, W1p, abias,
                                   Wop, W1pk, W2pk, Wqkvp, Wpairp);

  for (int l = 0; l < NLAYER; ++l) {
    int pi = l & 1, po = pi ^ 1;
    float* xin  = (l & 1) ? xb1 : xb0;
    float* xout = (l & 1) ? xb0 : xb1;

    k_attn2<<<dim3(48, 8), 256, ATTN_SMEM, stream>>>(qb[pi], kb[pi], vb[pi], abias, o);

    k_wo<<<dim3(48, 4), 256, 0, stream>>>(o, xin, Wop + ((size_t)l << 16), x1buf);

    k_ffn1<<<dim3(48, 16), 256, 0, stream>>>(
        x1buf, ln2_s + l * DM, ln2_b + l * DM,
        W1pk + ((size_t)l << 18), ffn_b1 + (size_t)l * DFF, Fg);

    k_ffn2<<<dim3(48, 16), 256, 0, stream>>>(
        Fg, x1buf, W2pk + ((size_t)l << 18), ffn_b2 + (size_t)l * DM, xout);

    if (l < NLAYER - 1) {
      k_t3<0><<<dim3(48, 12), 256, 0, stream>>>(
          xout, ln1_s + (l + 1) * DM, ln1_b + (l + 1) * DM,
          Wqkvp + (size_t)(l + 1) * 196608, nullptr, nullptr,
          qb[po], kb[po], vb[po]);
    } else {
      k_t3<1><<<dim3(48, 8), 256, 0, stream>>>(
          xout, lnf_s, lnf_b, Wpairp, pair_q_b, pair_k_b,
          pq, pk, nullptr);
    }
  }

  k_pair3<<<dim3(24, 192), 256, 0, stream>>>(pq, pk, W1p, RB, cls_w2, cls_b2, out);
}

// Round 16
// 610.946 us; speedup vs baseline: 1.0362x; 1.0362x over previous
//
#include <hip/hip_runtime.h>
#include <hip/hip_bf16.h>
#include <stdint.h>

// ---------------------------------------------------------------------------
#define LSEQ 768
#define DM   256
#define NH   8
#define DK   32
#define DFF  1024
#define NLAYER 8
#define NDD  1535
// ---------------------------------------------------------------------------

typedef __attribute__((ext_vector_type(8))) short     bf16x8;
typedef __attribute__((ext_vector_type(8))) _Float16  f16x8;
typedef __attribute__((ext_vector_type(4))) float     f32x4;

__device__ __forceinline__ unsigned short f2bf(float f) {
  unsigned u = __float_as_uint(f);
  u += 0x7fffu + ((u >> 16) & 1u);       // RNE
  return (unsigned short)(u >> 16);
}
__device__ __forceinline__ unsigned short f2h(float f) {
  union { _Float16 h; unsigned short s; } c;
  c.h = (_Float16)f;                     // v_cvt_f16_f32 (RNE)
  return c.s;
}
__device__ __forceinline__ int bucket_of(int dd) {
  int rel = dd - 767;
  int ret = rel < 0 ? 32 : 0;
  int arp = rel < 0 ? -rel : rel;
  if (arp < 16) return ret + arp;
  const float lr = 2.772588722239781f;   // float(np.log(16))
  float val = logf((float)arp * 0.0625f) / lr * 16.0f;
  int vi = 16 + (int)val;
  return ret + (vi < 31 ? vi : 31);
}

// ---------------------------------------------------------------------------
// MFMA B-fragment packers: row-major [K][N] fp32 -> [K/32][N/16][lane][8] fp16
// (lane layout: n = g*16 + (lane&15), k = kc*32 + (lane>>4)*8 + e)
__device__ __forceinline__ void pack8h(unsigned short* dst, int id,
                                       const float* src, int N, int G) {
  int lane = (id >> 3) & 63;
  int rem = id >> 9;
  int g = rem % G, kc = rem / G;
  int kb = kc * 32 + ((lane >> 4) << 3);
  int n = g * 16 + (lane & 15);
  union { unsigned short s[8]; uint4 v; } U;
  #pragma unroll
  for (int e = 0; e < 8; ++e) U.s[e] = f2h(src[(size_t)(kb + e) * N + n]);
  *(uint4*)(dst + id) = U.v;
}

// N-concat of up to 3 [K][256] matrices (qkv: G=48, pair q/k: G=32)
__device__ __forceinline__ void pack8h_cat(unsigned short* dst, int id,
                                           const float* s0, const float* s1,
                                           const float* s2, int G) {
  int lane = (id >> 3) & 63;
  int rem = id >> 9;
  int g = rem % G, kc = rem / G;
  int kb = kc * 32 + ((lane >> 4) << 3);
  int n = g * 16 + (lane & 15);
  const float* sp = n < 256 ? s0 : (n < 512 ? s1 : s2);
  int nn = n & 255;
  union { unsigned short s[8]; uint4 v; } U;
  #pragma unroll
  for (int e = 0; e < 8; ++e) U.s[e] = f2h(sp[(size_t)(kb + e) * 256 + nn]);
  *(uint4*)(dst + id) = U.v;
}

// ---------------------------------------------------------------------------
// Legacy 64x64 GEMM tile (k_prep only; plain caching, gather variants).
// LDS from smc: As 2x32x68 @0, Bs @17408, stat @34816, red @35328 -> 37376.
template <int LN, int GR>
__device__ void gemm_tile(const float* gsrc, const int* seqIdx,
                          const float* B, const float* bias, float* C,
                          const float* lns, const float* lnb,
                          int M, int K, int N, int m0, int n0, char* smc) {
  float (*As)[32][68] = (float (*)[32][68])smc;
  float (*Bs)[32][68] = (float (*)[32][68])(smc + 17408);
  float (*stat)[2]    = (float (*)[2])(smc + 34816);
  float (*red)[8]     = (float (*)[8])(smc + 35328);

  int t = threadIdx.x;
  int arow = t >> 2, akq = (t & 3) * 8;
  int mg = m0 + arow;
  int mgc = mg < M ? mg : M - 1;
  const float* Ar = (GR == 1) ? (gsrc + (size_t)seqIdx[mgc] * K)
                              : (gsrc + (size_t)bucket_of(mgc) * K);
  float mean = 0.f, rstd = 0.f;
  if (LN) {
    int lq = t & 3;
    float s = 0.f, s2 = 0.f;
    const float* p = Ar + lq * 64;
    #pragma unroll
    for (int c = 0; c < 64; c += 4) {
      float4 v = *(const float4*)(p + c);
      s  += v.x + v.y + v.z + v.w;
      s2 += v.x * v.x + v.y * v.y + v.z * v.z + v.w * v.w;
    }
    red[arow][lq] = s; red[arow][lq + 4] = s2;
    __syncthreads();
    if (lq == 0) {
      float sm = red[arow][0] + red[arow][1] + red[arow][2] + red[arow][3];
      float sq = red[arow][4] + red[arow][5] + red[arow][6] + red[arow][7];
      float m = sm * (1.f / 256.f);
      float v = sq * (1.f / 256.f) - m * m;
      stat[arow][0] = m;
      stat[arow][1] = rsqrtf(v + 1e-5f);
    }
    __syncthreads();
    mean = stat[arow][0]; rstd = stat[arow][1];
  }

  int bkr = t >> 3, bn8 = (t & 7) * 8;
  int ty = t >> 4, tx = t & 15;
  float acc[4][4] = {};
  int nk = K >> 5;

  for (int kt = 0; kt < nk; ++kt) {
    int k0 = kt << 5;
    float4 a0 = *(const float4*)(Ar + k0 + akq);
    float4 a1 = *(const float4*)(Ar + k0 + akq + 4);
    if (LN) {
      float4 ls0 = *(const float4*)(lns + k0 + akq), ls1 = *(const float4*)(lns + k0 + akq + 4);
      float4 lb0 = *(const float4*)(lnb + k0 + akq), lb1 = *(const float4*)(lnb + k0 + akq + 4);
      a0.x=(a0.x-mean)*rstd*ls0.x+lb0.x; a0.y=(a0.y-mean)*rstd*ls0.y+lb0.y;
      a0.z=(a0.z-mean)*rstd*ls0.z+lb0.z; a0.w=(a0.w-mean)*rstd*ls0.w+lb0.w;
      a1.x=(a1.x-mean)*rstd*ls1.x+lb1.x; a1.y=(a1.y-mean)*rstd*ls1.y+lb1.y;
      a1.z=(a1.z-mean)*rstd*ls1.z+lb1.z; a1.w=(a1.w-mean)*rstd*ls1.w+lb1.w;
    }
    int cur = kt & 1;
    As[cur][akq+0][arow]=a0.x; As[cur][akq+1][arow]=a0.y; As[cur][akq+2][arow]=a0.z; As[cur][akq+3][arow]=a0.w;
    As[cur][akq+4][arow]=a1.x; As[cur][akq+5][arow]=a1.y; As[cur][akq+6][arow]=a1.z; As[cur][akq+7][arow]=a1.w;
    *(float4*)&Bs[cur][bkr][bn8] = *(const float4*)(B + (size_t)(k0 + bkr) * N + n0 + bn8);
    *(float4*)&Bs[cur][bkr][bn8+4] = *(const float4*)(B + (size_t)(k0 + bkr) * N + n0 + bn8 + 4);
    __syncthreads();
    #pragma unroll 8
    for (int kk = 0; kk < 32; ++kk) {
      float4 a = *(float4*)&As[cur][kk][ty * 4];
      float4 b = *(float4*)&Bs[cur][kk][tx * 4];
      acc[0][0]=fmaf(a.x,b.x,acc[0][0]); acc[0][1]=fmaf(a.x,b.y,acc[0][1]);
      acc[0][2]=fmaf(a.x,b.z,acc[0][2]); acc[0][3]=fmaf(a.x,b.w,acc[0][3]);
      acc[1][0]=fmaf(a.y,b.x,acc[1][0]); acc[1][1]=fmaf(a.y,b.y,acc[1][1]);
      acc[1][2]=fmaf(a.y,b.z,acc[1][2]); acc[1][3]=fmaf(a.y,b.w,acc[1][3]);
      acc[2][0]=fmaf(a.z,b.x,acc[2][0]); acc[2][1]=fmaf(a.z,b.y,acc[2][1]);
      acc[2][2]=fmaf(a.z,b.z,acc[2][2]); acc[2][3]=fmaf(a.z,b.w,acc[2][3]);
      acc[3][0]=fmaf(a.w,b.x,acc[3][0]); acc[3][1]=fmaf(a.w,b.y,acc[3][1]);
      acc[3][2]=fmaf(a.w,b.z,acc[3][2]); acc[3][3]=fmaf(a.w,b.w,acc[3][3]);
    }
    __syncthreads();
  }

  #pragma unroll
  for (int u = 0; u < 4; ++u) {
    int m = m0 + ty * 4 + u;
    if (m < M) {
      int n = n0 + tx * 4;
      float4 val = make_float4(acc[u][0], acc[u][1], acc[u][2], acc[u][3]);
      if (bias) {
        float4 bv = *(const float4*)(bias + n);
        val.x += bv.x; val.y += bv.y; val.z += bv.z; val.w += bv.w;
      }
      *(float4*)(C + (size_t)m * N + n) = val;
    }
  }
}

// ---------------------------------------------------------------------------
// Prep: RB gemm + qkv layer0 + embed + abias + W1p pack + fp16 weight packs.
__global__ __launch_bounds__(256, 2) void k_prep(
    const int* __restrict__ seq, const float* __restrict__ tok_emb,
    const float* __restrict__ rp_emb,
    const float* __restrict__ wq, const float* __restrict__ wk,
    const float* __restrict__ wv, const float* __restrict__ wo,
    const float* __restrict__ ffn_w1, const float* __restrict__ ffn_w2,
    const float* __restrict__ ln1s0, const float* __restrict__ ln1b0,
    const float* __restrict__ pair_rp, const float* __restrict__ cls_w1,
    const float* __restrict__ cls_b1,
    const float* __restrict__ pair_q_w, const float* __restrict__ pair_k_w,
    float* x0, float* q0, float* k0, float* v0, float* RB,
    unsigned short* W1p, float* abias,
    unsigned short* Wop, unsigned short* W1pk, unsigned short* W2pk,
    unsigned short* Wqkvp, unsigned short* Wpairp) {
  __shared__ __align__(16) char sm[37376];
  int b = blockIdx.x, t = threadIdx.x;
  if (b < 96) {
    int m0 = (b % 24) * 64, n0 = (b / 24) * 64;
    gemm_tile<0,2>(pair_rp, nullptr, cls_w1, cls_b1, RB,
                   nullptr, nullptr, NDD, 256, 256, m0, n0, sm);
  } else if (b < 240) {
    int u = b - 96;
    int n0g = (u % 12) * 64, m0 = (u / 12) * 64;
    int bi = n0g >> 8, n0 = n0g & 255;
    const float* B = bi == 0 ? wq : (bi == 1 ? wk : wv);
    float* C = bi == 0 ? q0 : (bi == 1 ? k0 : v0);
    gemm_tile<1,1>(tok_emb, seq, B, nullptr, C,
                   ln1s0, ln1b0, LSEQ, 256, 256, m0, n0, sm);
  } else if (b < 432) {
    int row = (b - 240) * 4 + (t >> 6), c = (t & 63) * 4;
    *(float4*)(x0 + (size_t)row * DM + c) =
        *(const float4*)(tok_emb + (size_t)seq[row] * DM + c);
  } else if (b < 438) {
    int dd = (b - 432) * 256 + t;
    if (dd < NDD) {
      int bk = bucket_of(dd);
      #pragma unroll
      for (int h = 0; h < NH; ++h) abias[dd * 8 + h] = rp_emb[bk * 8 + h];
    }
  } else if (b < 502) {
    // cls_w1 pack -> fp16 fragments (consumed by k_pair3)
    int base = (b - 438) * 1024 + t * 4;
    #pragma unroll
    for (int uu = 0; uu < 4; ++uu) {
      int id = base + uu;
      int e = id & 7, lane = (id >> 3) & 63, g = (id >> 9) & 15, kc = id >> 13;
      int kg = kc * 32 + (lane >> 4) * 8 + e;
      int n  = g * 16 + (lane & 15);
      W1p[id] = f2h(cls_w1[(size_t)kg * 256 + n]);
    }
  } else {
    // fp16 MFMA weight packing: 3136 blocks x 2048 elems
    int u = (b - 502) * 2048 + t * 8;
    if (u < 524288) {                       // wo: 8 x [256][256], G=16
      int layer = u >> 16, id = u & 65535;
      pack8h(Wop + ((size_t)layer << 16), id, wo + ((size_t)layer << 16), 256, 16);
    } else if (u < 2621440) {               // ffn_w1: 8 x [256][1024], G=64
      int v2 = u - 524288; int layer = v2 >> 18, id = v2 & 262143;
      pack8h(W1pk + ((size_t)layer << 18), id, ffn_w1 + ((size_t)layer << 18), 1024, 64);
    } else if (u < 4718592) {               // ffn_w2: 8 x [1024][256], G=16
      int v2 = u - 2621440; int layer = v2 >> 18, id = v2 & 262143;
      pack8h(W2pk + ((size_t)layer << 18), id, ffn_w2 + ((size_t)layer << 18), 256, 16);
    } else if (u < 6291456) {               // qkv concat: 8 x [256][768], G=48
      int v2 = u - 4718592; int layer = v2 / 196608, id = v2 - layer * 196608;
      pack8h_cat(Wqkvp + (size_t)layer * 196608, id,
                 wq + ((size_t)layer << 16), wk + ((size_t)layer << 16),
                 wv + ((size_t)layer << 16), 48);
    } else {                                // pair q/k concat: [256][512], G=32
      int id = u - 6291456;
      pack8h_cat(Wpairp, id, pair_q_w, pair_k_w, pair_k_w, 32);
    }
  }
}

// ---------------------------------------------------------------------------
// Attention (validated round 7): 16 q-rows x 1 head per block.
#define ATTN_SMEM 72960

__global__ __launch_bounds__(256, 2) void k_attn2(
    const float* __restrict__ q, const float* __restrict__ k,
    const float* __restrict__ v, const float* __restrict__ abias,
    float* __restrict__ o) {
  extern __shared__ char sm[];
  float* S  = (float*)sm;
  float* KV = (float*)(sm + 49664);
  float* QS = (float*)(sm + 66560);
  float* BS = (float*)(sm + 68672);
  float (*red)[16] = (float (*)[16])(sm + 71808);
  float* mrow = (float*)(sm + 72832);
  float* linv = (float*)(sm + 72896);

  int i0 = blockIdx.x * 16, h = blockIdx.y, hc = h * DK;
  int t = threadIdx.x;

  for (int u = t; u < 783; u += 256)
    BS[u] = abias[(size_t)(i0 + u) * 8 + h];
  {
    int r = t >> 4, c = t & 15;
    const float inv = 0.17677669529663687f;   // 1/sqrt(32)
    QS[r * 33 + c]      = q[(size_t)(i0 + r) * DM + hc + c] * inv;
    QS[r * 33 + c + 16] = q[(size_t)(i0 + r) * DM + hc + c + 16] * inv;
  }

  int kx = t & 31, ry = t >> 5;
  int key = t >> 1, half = t & 1;

  for (int cc = 0; cc < 6; ++cc) {
    const float* kp = k + (size_t)(cc * 128 + key) * DM + hc + half * 16;
    float4 L0 = *(const float4*)(kp);
    float4 L1 = *(const float4*)(kp + 4);
    float4 L2 = *(const float4*)(kp + 8);
    float4 L3 = *(const float4*)(kp + 12);
    __syncthreads();
    int cb = half * 16;
    KV[(cb+ 0)*132+key]=L0.x; KV[(cb+ 1)*132+key]=L0.y; KV[(cb+ 2)*132+key]=L0.z; KV[(cb+ 3)*132+key]=L0.w;
    KV[(cb+ 4)*132+key]=L1.x; KV[(cb+ 5)*132+key]=L1.y; KV[(cb+ 6)*132+key]=L1.z; KV[(cb+ 7)*132+key]=L1.w;
    KV[(cb+ 8)*132+key]=L2.x; KV[(cb+ 9)*132+key]=L2.y; KV[(cb+10)*132+key]=L2.z; KV[(cb+11)*132+key]=L2.w;
    KV[(cb+12)*132+key]=L3.x; KV[(cb+13)*132+key]=L3.y; KV[(cb+14)*132+key]=L3.z; KV[(cb+15)*132+key]=L3.w;
    __syncthreads();

    float s0x=0,s0y=0,s0z=0,s0w=0, s1x=0,s1y=0,s1z=0,s1w=0;
    #pragma unroll
    for (int kk = 0; kk < 32; ++kk) {
      float q0 = QS[(ry*2    )*33 + kk];
      float q1 = QS[(ry*2 + 1)*33 + kk];
      float4 kv4 = *(const float4*)&KV[kk*132 + kx*4];
      s0x = fmaf(q0, kv4.x, s0x); s0y = fmaf(q0, kv4.y, s0y);
      s0z = fmaf(q0, kv4.z, s0z); s0w = fmaf(q0, kv4.w, s0w);
      s1x = fmaf(q1, kv4.x, s1x); s1y = fmaf(q1, kv4.y, s1y);
      s1z = fmaf(q1, kv4.z, s1z); s1w = fmaf(q1, kv4.w, s1w);
    }
    int jb = cc * 128 + kx * 4;
    int r0 = ry * 2, r1 = r0 + 1;
    S[r0*776 + jb+0] = s0x + BS[r0 + 767 - (jb+0)];
    S[r0*776 + jb+1] = s0y + BS[r0 + 767 - (jb+1)];
    S[r0*776 + jb+2] = s0z + BS[r0 + 767 - (jb+2)];
    S[r0*776 + jb+3] = s0w + BS[r0 + 767 - (jb+3)];
    S[r1*776 + jb+0] = s1x + BS[r1 + 767 - (jb+0)];
    S[r1*776 + jb+1] = s1y + BS[r1 + 767 - (jb+1)];
    S[r1*776 + jb+2] = s1z + BS[r1 + 767 - (jb+2)];
    S[r1*776 + jb+3] = s1w + BS[r1 + 767 - (jb+3)];
  }
  __syncthreads();

  {
    int ti = t >> 4, tj = t & 15;
    float mx = -1e30f;
    for (int jc = 0; jc < 48; ++jc)
      mx = fmaxf(mx, S[ti*776 + jc*16 + tj]);
    red[ti][tj] = mx;
    __syncthreads();
    if (tj == 0) {
      float m2 = red[ti][0];
      #pragma unroll
      for (int u = 1; u < 16; ++u) m2 = fmaxf(m2, red[ti][u]);
      mrow[ti] = m2;
    }
    __syncthreads();
    float m2 = mrow[ti];
    float sum = 0.f;
    for (int jc = 0; jc < 48; ++jc) {
      int j = jc*16 + tj;
      float e = __expf(S[ti*776 + j] - m2);
      S[ti*776 + j] = e;
      sum += e;
    }
    red[ti][tj] = sum;
    __syncthreads();
    if (tj == 0) {
      float s2 = 0.f;
      #pragma unroll
      for (int u = 0; u < 16; ++u) s2 += red[ti][u];
      linv[ti] = 1.f / s2;
    }
  }

  int cp = t & 15, jg = t >> 4;
  int c0 = cp * 2, c1 = c0 + 1;
  float oc0[16] = {}, oc1[16] = {};
  for (int cc = 0; cc < 6; ++cc) {
    const float* vp = v + (size_t)(cc * 128 + key) * DM + hc + half * 16;
    float4 L0 = *(const float4*)(vp);
    float4 L1 = *(const float4*)(vp + 4);
    float4 L2 = *(const float4*)(vp + 8);
    float4 L3 = *(const float4*)(vp + 12);
    __syncthreads();
    int cb = half * 16;
    KV[(cb+ 0)*132+key]=L0.x; KV[(cb+ 1)*132+key]=L0.y; KV[(cb+ 2)*132+key]=L0.z; KV[(cb+ 3)*132+key]=L0.w;
    KV[(cb+ 4)*132+key]=L1.x; KV[(cb+ 5)*132+key]=L1.y; KV[(cb+ 6)*132+key]=L1.z; KV[(cb+ 7)*132+key]=L1.w;
    KV[(cb+ 8)*132+key]=L2.x; KV[(cb+ 9)*132+key]=L2.y; KV[(cb+10)*132+key]=L2.z; KV[(cb+11)*132+key]=L2.w;
    KV[(cb+12)*132+key]=L3.x; KV[(cb+13)*132+key]=L3.y; KV[(cb+14)*132+key]=L3.z; KV[(cb+15)*132+key]=L3.w;
    __syncthreads();

    #pragma unroll
    for (int jj2 = 0; jj2 < 2; ++jj2) {
      int jb = jg * 8 + jj2 * 4;
      float4 vA = *(const float4*)&KV[c0*132 + jb];
      float4 vB = *(const float4*)&KV[c1*132 + jb];
      #pragma unroll
      for (int r = 0; r < 16; ++r) {
        float4 sv = *(const float4*)&S[r*776 + cc*128 + jb];
        oc0[r] += sv.x*vA.x + sv.y*vA.y + sv.z*vA.z + sv.w*vA.w;
        oc1[r] += sv.x*vB.x + sv.y*vB.y + sv.z*vB.z + sv.w*vB.w;
      }
    }
  }

  #pragma unroll
  for (int h2 = 0; h2 < 2; ++h2) {
    __syncthreads();
    #pragma unroll
    for (int r = 0; r < 8; ++r) {
      KV[(jg*8 + r)*32 + c0] = oc0[h2*8 + r];
      KV[(jg*8 + r)*32 + c1] = oc1[h2*8 + r];
    }
    __syncthreads();
    int r = t >> 5, c = t & 31;
    float s = 0.f;
    #pragma unroll
    for (int jgg = 0; jgg < 16; ++jgg) s += KV[(jgg*8 + r)*32 + c];
    o[(size_t)(i0 + h2*8 + r) * DM + hc + c] = s * linv[h2*8 + r];
  }
}

// ---------------------------------------------------------------------------
// Layer tail, wave-maximized (validated round 7): 1 16x16 MFMA tile per wave.

// k_wo: X1 = xin + O@Wo. grid (48,4) x 256thr; wave w -> g = by*4+w.
__global__ __launch_bounds__(256, 2) void k_wo(
    const float* __restrict__ o, const float* __restrict__ xin,
    const unsigned short* __restrict__ wop, float* __restrict__ x1) {
  __shared__ __align__(16) _Float16 Ab[16][264];
  int t = threadIdx.x;
  int i0 = blockIdx.x * 16;
  int by = blockIdx.y;
  int w = t >> 6, l = t & 63;
  int lr = l & 15, lq = l >> 4;

  {
    int r = t >> 4, j = t & 15;
    #pragma unroll
    for (int q = 0; q < 4; ++q) {
      int c = j * 4 + q * 64;
      float4 v = *(const float4*)(o + (size_t)(i0 + r) * DM + c);
      union { _Float16 h[4]; uint2 u; } cv;
      cv.h[0] = (_Float16)v.x; cv.h[1] = (_Float16)v.y;
      cv.h[2] = (_Float16)v.z; cv.h[3] = (_Float16)v.w;
      *(uint2*)&Ab[r][c] = cv.u;
    }
  }
  __syncthreads();

  f16x8 af[8];
  #pragma unroll
  for (int kc = 0; kc < 8; ++kc)
    af[kc] = *(const f16x8*)&Ab[lr][kc * 32 + lq * 8];

  int g = by * 4 + w;
  const unsigned short* wp = wop + (size_t)l * 8;
  f32x4 ac = {0.f, 0.f, 0.f, 0.f};
  #pragma unroll
  for (int kc = 0; kc < 8; ++kc) {
    f16x8 bb = *(const f16x8*)(wp + ((kc * 16 + g) << 9));
    ac = __builtin_amdgcn_mfma_f32_16x16x32_f16(af[kc], bb, ac, 0, 0, 0);
  }
  int n = g * 16 + lr;
  #pragma unroll
  for (int r = 0; r < 4; ++r) {
    int row = i0 + lq * 4 + r;
    x1[(size_t)row * DM + n] = xin[(size_t)row * DM + n] + ac[r];
  }
}

// k_ffn1: LN2(x1) -> ffn1 chunk + gelu -> Fg. grid (48,16); wave -> g = by*4+w.
__global__ __launch_bounds__(256, 2) void k_ffn1(
    const float* __restrict__ x1,
    const float* __restrict__ ln2s, const float* __restrict__ ln2b,
    const unsigned short* __restrict__ w1p, const float* __restrict__ fb1,
    unsigned short* __restrict__ Fg) {
  __shared__ __align__(16) _Float16 Ab[16][264];
  int t = threadIdx.x;
  int i0 = blockIdx.x * 16;
  int by = blockIdx.y;
  int w = t >> 6, l = t & 63;
  int lr = l & 15, lq = l >> 4;

  // LN2 from global x1 (16 threads/row, shuffle reduce) -> Ab fp16
  {
    int r = t >> 4, j = t & 15;
    int c0 = j * 16;
    const float* xp = x1 + (size_t)(i0 + r) * DM + c0;
    float xv[16]; float s1 = 0.f, s2 = 0.f;
    #pragma unroll
    for (int u = 0; u < 16; u += 4) {
      float4 v = *(const float4*)(xp + u);
      xv[u] = v.x; xv[u+1] = v.y; xv[u+2] = v.z; xv[u+3] = v.w;
      s1 += v.x + v.y + v.z + v.w;
      s2 += v.x*v.x + v.y*v.y + v.z*v.z + v.w*v.w;
    }
    #pragma unroll
    for (int m = 1; m < 16; m <<= 1) {
      s1 += __shfl_xor(s1, m);
      s2 += __shfl_xor(s2, m);
    }
    float mean = s1 * (1.f / 256.f);
    float var  = s2 * (1.f / 256.f) - mean * mean;
    float rs = rsqrtf(var + 1e-5f);
    #pragma unroll
    for (int p = 0; p < 4; ++p) {
      union { _Float16 h[4]; uint2 u; } cv;
      #pragma unroll
      for (int e = 0; e < 4; ++e) {
        int c = c0 + p * 4 + e;
        cv.h[e] = (_Float16)((xv[p * 4 + e] - mean) * rs * ln2s[c] + ln2b[c]);
      }
      *(uint2*)&Ab[r][c0 + p * 4] = cv.u;
    }
  }
  __syncthreads();

  f16x8 af[8];
  #pragma unroll
  for (int kc = 0; kc < 8; ++kc)
    af[kc] = *(const f16x8*)&Ab[lr][kc * 32 + lq * 8];

  int g = by * 4 + w;
  const unsigned short* wp = w1p + (size_t)l * 8;
  f32x4 ac = {0.f, 0.f, 0.f, 0.f};
  #pragma unroll
  for (int kc = 0; kc < 8; ++kc) {
    f16x8 bb = *(const f16x8*)(wp + ((kc * 64 + g) << 9));
    ac = __builtin_amdgcn_mfma_f32_16x16x32_f16(af[kc], bb, ac, 0, 0, 0);
  }
  int n = g * 16 + lr;
  float b1 = fb1[n];
  #pragma unroll
  for (int r = 0; r < 4; ++r) {
    float v = ac[r] + b1;
    v = 0.5f * v * (1.f + erff(v * 0.70710678118654752f));
    Fg[(size_t)(i0 + lq * 4 + r) * DFF + n] = f2h(v);
  }
}

// k_ffn2: X2 = X1 + F@W2 + b2. grid (48,16); block = one 16x16 tile (g = by),
// 4 waves K-split K=1024 (256 each), LDS partial reduce, wave 0 writes.
__global__ __launch_bounds__(256, 2) void k_ffn2(
    const unsigned short* __restrict__ Fg, const float* __restrict__ x1,
    const unsigned short* __restrict__ w2p, const float* __restrict__ fb2,
    float* __restrict__ x2) {
  __shared__ __align__(16) _Float16 Fs[16][1032];
  __shared__ float part[3][16][17];
  int t = threadIdx.x;
  int i0 = blockIdx.x * 16;
  int g = blockIdx.y;
  int w = t >> 6, l = t & 63;
  int lr = l & 15, lq = l >> 4;

  {
    int r = t >> 4, j = t & 15;
    #pragma unroll
    for (int q = 0; q < 8; ++q) {
      int c = j * 8 + q * 128;
      *(uint4*)&Fs[r][c] = *(const uint4*)(Fg + (size_t)(i0 + r) * DFF + c);
    }
  }
  __syncthreads();

  const unsigned short* wp = w2p + (size_t)l * 8;
  f32x4 ac = {0.f, 0.f, 0.f, 0.f};
  #pragma unroll
  for (int k8 = 0; k8 < 8; ++k8) {
    int kc = w * 8 + k8;
    f16x8 fa = *(const f16x8*)&Fs[lr][kc * 32 + lq * 8];
    f16x8 bb = *(const f16x8*)(wp + ((kc * 16 + g) << 9));
    ac = __builtin_amdgcn_mfma_f32_16x16x32_f16(fa, bb, ac, 0, 0, 0);
  }
  if (w > 0) {
    #pragma unroll
    for (int r = 0; r < 4; ++r)
      part[w - 1][lq * 4 + r][lr] = ac[r];
  }
  __syncthreads();
  if (w == 0) {
    int n = g * 16 + lr;
    float b2v = fb2[n];
    #pragma unroll
    for (int r = 0; r < 4; ++r) {
      int rr = lq * 4 + r;
      int row = i0 + rr;
      float s = ac[r] + part[0][rr][lr] + part[1][rr][lr] + part[2][rr][lr];
      x2[(size_t)row * DM + n] = x1[(size_t)row * DM + n] + s + b2v;
    }
  }
}

// k_t3: LN1next/LNf + qkv chunk (or pair projection). 1 g per wave.
// grid (48,12) for qkv (G=48), (48,8) for pair (G=32).
template <int LAST>
__global__ __launch_bounds__(256, 2) void k_t3(
    const float* __restrict__ x2,
    const float* __restrict__ lns, const float* __restrict__ lnb,
    const unsigned short* __restrict__ wnp,
    const float* __restrict__ nb0, const float* __restrict__ nb1,
    float* __restrict__ qo, float* __restrict__ ko, float* __restrict__ vo) {
  __shared__ __align__(16) _Float16 Ab[16][264];
  int t = threadIdx.x;
  int i0 = blockIdx.x * 16;
  int by = blockIdx.y;
  int w = t >> 6, l = t & 63;
  int lr = l & 15, lq = l >> 4;

  {
    int r = t >> 4, j = t & 15;
    int c0 = j * 16;
    const float* xp = x2 + (size_t)(i0 + r) * DM + c0;
    float xv[16]; float s1 = 0.f, s2 = 0.f;
    #pragma unroll
    for (int u = 0; u < 16; u += 4) {
      float4 v = *(const float4*)(xp + u);
      xv[u] = v.x; xv[u+1] = v.y; xv[u+2] = v.z; xv[u+3] = v.w;
      s1 += v.x + v.y + v.z + v.w;
      s2 += v.x*v.x + v.y*v.y + v.z*v.z + v.w*v.w;
    }
    #pragma unroll
    for (int m = 1; m < 16; m <<= 1) {
      s1 += __shfl_xor(s1, m);
      s2 += __shfl_xor(s2, m);
    }
    float mean = s1 * (1.f / 256.f);
    float var  = s2 * (1.f / 256.f) - mean * mean;
    float rs = rsqrtf(var + 1e-5f);
    #pragma unroll
    for (int p = 0; p < 4; ++p) {
      union { _Float16 h[4]; uint2 u; } cv;
      #pragma unroll
      for (int e = 0; e < 4; ++e) {
        int c = c0 + p * 4 + e;
        cv.h[e] = (_Float16)((xv[p * 4 + e] - mean) * rs * lns[c] + lnb[c]);
      }
      *(uint2*)&Ab[r][c0 + p * 4] = cv.u;
    }
  }
  __syncthreads();

  f16x8 af[8];
  #pragma unroll
  for (int kc = 0; kc < 8; ++kc)
    af[kc] = *(const f16x8*)&Ab[lr][kc * 32 + lq * 8];

  const unsigned short* wp = wnp + (size_t)l * 8;
  int g = by * 4 + w;
  if (!LAST) {
    f32x4 ac = {0.f, 0.f, 0.f, 0.f};
    #pragma unroll
    for (int kc = 0; kc < 8; ++kc) {
      f16x8 bb = *(const f16x8*)(wp + ((kc * 48 + g) << 9));
      ac = __builtin_amdgcn_mfma_f32_16x16x32_f16(af[kc], bb, ac, 0, 0, 0);
    }
    int n = g * 16 + lr;
    float* dst = n < 256 ? qo : (n < 512 ? ko : vo);
    int nn = n & 255;
    #pragma unroll
    for (int r = 0; r < 4; ++r)
      dst[(size_t)(i0 + lq * 4 + r) * DM + nn] = ac[r];
  } else {
    f32x4 ac = {0.f, 0.f, 0.f, 0.f};
    #pragma unroll
    for (int kc = 0; kc < 8; ++kc) {
      f16x8 bb = *(const f16x8*)(wp + ((kc * 32 + g) << 9));
      ac = __builtin_amdgcn_mfma_f32_16x16x32_f16(af[kc], bb, ac, 0, 0, 0);
    }
    int n = g * 16 + lr;
    float* dst = n < 256 ? qo : ko;
    const float* bias = n < 256 ? nb0 : nb1;
    int nn = n & 255;
    float bv = bias[nn];
    #pragma unroll
    for (int r = 0; r < 4; ++r)
      dst[(size_t)(i0 + lq * 4 + r) * DM + nn] = ac[r] + bv;
  }
}

// ---------------------------------------------------------------------------
// Fused pair head v5 (validated round 12, session best): fp32 RB_s LDS
// staging, fp16 q/k staging, pk_mul + f16 MFMA, disjoint-store epilogue
// racc2[nwv][r][2] + final 2-way add (no atomics).
__global__ __launch_bounds__(256, 2) void k_pair3(
    const float* __restrict__ pq, const float* __restrict__ pk,
    const unsigned short* __restrict__ W1p, const float* __restrict__ RB,
    const float* __restrict__ w2, const float* __restrict__ b2,
    float* __restrict__ out) {
  __shared__ __align__(16) _Float16 qsh[4][264];
  __shared__ __align__(16) _Float16 ksh[32][264];
  __shared__ __align__(16) float    RB_s[35][260];
  __shared__ float racc2[2][128][2];

  int t = threadIdx.x;
  int j0 = blockIdx.x * 32;
  int i0 = blockIdx.y * 4;
  int w = t >> 6, l = t & 63;
  int q4 = l >> 4, l15 = l & 15;
  int mwv = w & 1, nwv = w >> 1;

  // stage q (4x256) + k (32x256) as fp16, RB tile as fp32
  {
    if (t < 128) {
      int kr = t >> 5, c8 = (t & 31) * 8;
      const float* sp = pq + (size_t)(i0 + kr) * DM + c8;
      float4 a = *(const float4*)sp, b = *(const float4*)(sp + 4);
      f16x8 h;
      h[0]=(_Float16)a.x; h[1]=(_Float16)a.y; h[2]=(_Float16)a.z; h[3]=(_Float16)a.w;
      h[4]=(_Float16)b.x; h[5]=(_Float16)b.y; h[6]=(_Float16)b.z; h[7]=(_Float16)b.w;
      *(f16x8*)&qsh[kr][c8] = h;
    }
    #pragma unroll
    for (int r8 = 0; r8 < 4; ++r8) {
      int idx = t + r8 * 256;
      int kr = idx >> 5, c8 = (idx & 31) * 8;
      const float* sp = pk + (size_t)(j0 + kr) * DM + c8;
      float4 a = *(const float4*)sp, b = *(const float4*)(sp + 4);
      f16x8 h;
      h[0]=(_Float16)a.x; h[1]=(_Float16)a.y; h[2]=(_Float16)a.z; h[3]=(_Float16)a.w;
      h[4]=(_Float16)b.x; h[5]=(_Float16)b.y; h[6]=(_Float16)b.z; h[7]=(_Float16)b.w;
      *(f16x8*)&ksh[kr][c8] = h;
    }
    int ddmin = i0 - j0 + 736;
    for (int idx = t; idx < 35 * 64; idx += 256) {
      int lc = idx >> 6, c4b = (idx & 63) * 4;
      *(float4*)&RB_s[lc][c4b] =
          *(const float4*)(RB + (size_t)(ddmin + lc) * 256 + c4b);
    }
  }
  __syncthreads();

  const unsigned short* Bp = W1p + (size_t)(nwv * 8) * 512 + (size_t)l * 8;

  f32x4 acc[4][8];
  #pragma unroll
  for (int aa = 0; aa < 4; ++aa)
    #pragma unroll
    for (int bb = 0; bb < 8; ++bb) acc[aa][bb] = (f32x4){0.f, 0.f, 0.f, 0.f};

  f16x8 bcur[8];
  #pragma unroll
  for (int nt = 0; nt < 8; ++nt) bcur[nt] = *(const f16x8*)(Bp + nt * 512);

  for (int kc = 0; kc < 8; ++kc) {
    f16x8 bnxt[8];
    if (kc < 7) {
      const unsigned short* bbn = Bp + (size_t)(kc + 1) * 8192;
      #pragma unroll
      for (int nt = 0; nt < 8; ++nt) bnxt[nt] = *(const f16x8*)(bbn + nt * 512);
    }
    int c = kc * 32 + q4 * 8;
    f16x8 qa = *(const f16x8*)&qsh[mwv * 2][c];
    f16x8 qb = *(const f16x8*)&qsh[mwv * 2 + 1][c];
    f16x8 ka = *(const f16x8*)&ksh[l15][c];
    f16x8 kb = *(const f16x8*)&ksh[16 + l15][c];

    f16x8 af0 = qa * ka;   // v_pk_mul_f16 x4
    f16x8 af1 = qa * kb;
    f16x8 af2 = qb * ka;
    f16x8 af3 = qb * kb;

    #pragma unroll
    for (int nt = 0; nt < 8; ++nt) {
      acc[0][nt] = __builtin_amdgcn_mfma_f32_16x16x32_f16(af0, bcur[nt], acc[0][nt], 0, 0, 0);
      acc[1][nt] = __builtin_amdgcn_mfma_f32_16x16x32_f16(af1, bcur[nt], acc[1][nt], 0, 0, 0);
      acc[2][nt] = __builtin_amdgcn_mfma_f32_16x16x32_f16(af2, bcur[nt], acc[2][nt], 0, 0, 0);
      acc[3][nt] = __builtin_amdgcn_mfma_f32_16x16x32_f16(af3, bcur[nt], acc[3][nt], 0, 0, 0);
    }
    if (kc < 7) {
      #pragma unroll
      for (int nt = 0; nt < 8; ++nt) bcur[nt] = bnxt[nt];
    }
  }

  float w20[8], w21[8];
  #pragma unroll
  for (int nt = 0; nt < 8; ++nt) {
    int n = nwv * 128 + nt * 16 + l15;
    w20[nt] = w2[n * 2];
    w21[nt] = w2[n * 2 + 1];
  }
  #pragma unroll
  for (int mt = 0; mt < 4; ++mt) {
    #pragma unroll
    for (int reg = 0; reg < 4; ++reg) {
      int r = mwv * 64 + mt * 16 + q4 * 4 + reg;
      int lc = (r >> 5) - (r & 31) + 31;
      float o0 = 0.f, o1 = 0.f;
      #pragma unroll
      for (int nt = 0; nt < 8; ++nt) {
        int n = nwv * 128 + nt * 16 + l15;
        float T = acc[mt][nt][reg] + RB_s[lc][n];
        T = fmaxf(T, 0.f);
        o0 = fmaf(T, w20[nt], o0);
        o1 = fmaf(T, w21[nt], o1);
      }
      #pragma unroll
      for (int s = 1; s < 16; s <<= 1) {
        o0 += __shfl_xor(o0, s);
        o1 += __shfl_xor(o1, s);
      }
      if (l15 == 0) {
        racc2[nwv][r][0] = o0;
        racc2[nwv][r][1] = o1;
      }
    }
  }
  __syncthreads();
  {
    int r = t >> 1, oo = t & 1;
    out[((size_t)(i0 + (r >> 5)) * LSEQ + (j0 + (r & 31))) * 2 + oo] =
        racc2[0][r][oo] + racc2[1][r][oo] + b2[oo];
  }
}

// ---------------------------------------------------------------------------
extern "C" void kernel_launch(void* const* d_in, const int* in_sizes, int n_in,
                              void* d_out, int out_size, void* d_ws, size_t ws_size,
                              hipStream_t stream) {
  const int*   seq      = (const int*)  d_in[0];
  const float* tok_emb  = (const float*)d_in[1];
  const float* rp_emb   = (const float*)d_in[2];
  const float* wq       = (const float*)d_in[3];
  const float* wk       = (const float*)d_in[4];
  const float* wv       = (const float*)d_in[5];
  const float* wo       = (const float*)d_in[6];
  const float* ln1_s    = (const float*)d_in[7];
  const float* ln1_b    = (const float*)d_in[8];
  const float* ln2_s    = (const float*)d_in[9];
  const float* ln2_b    = (const float*)d_in[10];
  const float* ffn_w1   = (const float*)d_in[11];
  const float* ffn_b1   = (const float*)d_in[12];
  const float* ffn_w2   = (const float*)d_in[13];
  const float* ffn_b2   = (const float*)d_in[14];
  const float* lnf_s    = (const float*)d_in[15];
  const float* lnf_b    = (const float*)d_in[16];
  const float* pair_q_w = (const float*)d_in[17];
  const float* pair_q_b = (const float*)d_in[18];
  const float* pair_k_w = (const float*)d_in[19];
  const float* pair_k_b = (const float*)d_in[20];
  const float* pair_rp  = (const float*)d_in[21];
  const float* cls_w1   = (const float*)d_in[22];
  const float* cls_b1   = (const float*)d_in[23];
  const float* cls_w2   = (const float*)d_in[24];
  const float* cls_b2   = (const float*)d_in[25];
  float* out = (float*)d_out;

  char* ws = (char*)d_ws;
  float* xb0 = (float*)(ws + 0);
  float* xb1 = (float*)(ws + 786432);
  float* qb[2] = { (float*)(ws + 1572864), (float*)(ws + 3932160) };
  float* kb[2] = { (float*)(ws + 2359296), (float*)(ws + 4718592) };
  float* vb[2] = { (float*)(ws + 3145728), (float*)(ws + 5505024) };
  float* o   = (float*)(ws + 6291456);
  float* pq  = (float*)(ws + 7077888);
  float* pk  = (float*)(ws + 7864320);
  float* RB  = (float*)(ws + 8650752);
  unsigned short* W1p = (unsigned short*)(ws + 10223616);
  float* abias = (float*)(ws + 10354688);
  // packed fp16 MFMA weights
  unsigned short* Wop    = (unsigned short*)(ws + 10403840);  // 8 x 65536  x2B
  unsigned short* W1pk   = (unsigned short*)(ws + 11452416);  // 8 x 262144 x2B
  unsigned short* W2pk   = (unsigned short*)(ws + 15646720);  // 8 x 262144 x2B
  unsigned short* Wqkvp  = (unsigned short*)(ws + 19841024);  // 8 x 196608 x2B
  unsigned short* Wpairp = (unsigned short*)(ws + 22986752);  // 131072 x2B
  unsigned short* Fg     = (unsigned short*)(ws + 23248896);  // 768x1024 fp16
  float* x1buf           = (float*)(ws + 24821760);           // 768x256 f32

  (void)in_sizes; (void)n_in; (void)out_size; (void)ws_size;

  hipFuncSetAttribute(reinterpret_cast<const void*>(k_attn2),
                      hipFuncAttributeMaxDynamicSharedMemorySize, ATTN_SMEM);

  k_prep<<<3638, 256, 0, stream>>>(seq, tok_emb, rp_emb, wq, wk, wv, wo,
                                   ffn_w1, ffn_w2, ln1_s, ln1_b,
                                   pair_rp, cls_w1, cls_b1, pair_q_w, pair_k_w,
                                   xb0, qb[0], kb[0], vb[0], RB, W1p, abias,
                                   Wop, W1pk, W2pk, Wqkvp, Wpairp);

  for (int l = 0; l < NLAYER; ++l) {
    int pi = l & 1, po = pi ^ 1;
    float* xin  = (l & 1) ? xb1 : xb0;
    float* xout = (l & 1) ? xb0 : xb1;

    k_attn2<<<dim3(48, 8), 256, ATTN_SMEM, stream>>>(qb[pi], kb[pi], vb[pi], abias, o);

    k_wo<<<dim3(48, 4), 256, 0, stream>>>(o, xin, Wop + ((size_t)l << 16), x1buf);

    k_ffn1<<<dim3(48, 16), 256, 0, stream>>>(
        x1buf, ln2_s + l * DM, ln2_b + l * DM,
        W1pk + ((size_t)l << 18), ffn_b1 + (size_t)l * DFF, Fg);

    k_ffn2<<<dim3(48, 16), 256, 0, stream>>>(
        Fg, x1buf, W2pk + ((size_t)l << 18), ffn_b2 + (size_t)l * DM, xout);

    if (l < NLAYER - 1) {
      k_t3<0><<<dim3(48, 12), 256, 0, stream>>>(
          xout, ln1_s + (l + 1) * DM, ln1_b + (l + 1) * DM,
          Wqkvp + (size_t)(l + 1) * 196608, nullptr, nullptr,
          qb[po], kb[po], vb[po]);
    } else {
      k_t3<1><<<dim3(48, 8), 256, 0, stream>>>(
          xout, lnf_s, lnf_b, Wpairp, pair_q_b, pair_k_b,
          pq, pk, nullptr);
    }
  }

  k_pair3<<<dim3(24, 192), 256, 0, stream>>>(pq, pk, W1p, RB, cls_w2, cls_b2, out);
}

// Round 17
// 610.554 us; speedup vs baseline: 1.0369x; 1.0006x over previous
//
#include <hip/hip_runtime.h>
#include <hip/hip_bf16.h>
#include <stdint.h>

// ---------------------------------------------------------------------------
#define LSEQ 768
#define DM   256
#define NH   8
#define DK   32
#define DFF  1024
#define NLAYER 8
#define NDD  1535
// ---------------------------------------------------------------------------

typedef __attribute__((ext_vector_type(8))) short     bf16x8;
typedef __attribute__((ext_vector_type(8))) _Float16  f16x8;
typedef __attribute__((ext_vector_type(4))) float     f32x4;

__device__ __forceinline__ unsigned short f2bf(float f) {
  unsigned u = __float_as_uint(f);
  u += 0x7fffu + ((u >> 16) & 1u);       // RNE
  return (unsigned short)(u >> 16);
}
__device__ __forceinline__ unsigned short f2h(float f) {
  union { _Float16 h; unsigned short s; } c;
  c.h = (_Float16)f;                     // v_cvt_f16_f32 (RNE)
  return c.s;
}
__device__ __forceinline__ int bucket_of(int dd) {
  int rel = dd - 767;
  int ret = rel < 0 ? 32 : 0;
  int arp = rel < 0 ? -rel : rel;
  if (arp < 16) return ret + arp;
  const float lr = 2.772588722239781f;   // float(np.log(16))
  float val = logf((float)arp * 0.0625f) / lr * 16.0f;
  int vi = 16 + (int)val;
  return ret + (vi < 31 ? vi : 31);
}

// ---------------------------------------------------------------------------
// MFMA B-fragment packers: row-major [K][N] fp32 -> [K/32][N/16][lane][8] fp16
// (lane layout: n = g*16 + (lane&15), k = kc*32 + (lane>>4)*8 + e)
__device__ __forceinline__ void pack8h(unsigned short* dst, int id,
                                       const float* src, int N, int G) {
  int lane = (id >> 3) & 63;
  int rem = id >> 9;
  int g = rem % G, kc = rem / G;
  int kb = kc * 32 + ((lane >> 4) << 3);
  int n = g * 16 + (lane & 15);
  union { unsigned short s[8]; uint4 v; } U;
  #pragma unroll
  for (int e = 0; e < 8; ++e) U.s[e] = f2h(src[(size_t)(kb + e) * N + n]);
  *(uint4*)(dst + id) = U.v;
}

// N-concat of up to 3 [K][256] matrices (qkv: G=48, pair q/k: G=32)
__device__ __forceinline__ void pack8h_cat(unsigned short* dst, int id,
                                           const float* s0, const float* s1,
                                           const float* s2, int G) {
  int lane = (id >> 3) & 63;
  int rem = id >> 9;
  int g = rem % G, kc = rem / G;
  int kb = kc * 32 + ((lane >> 4) << 3);
  int n = g * 16 + (lane & 15);
  const float* sp = n < 256 ? s0 : (n < 512 ? s1 : s2);
  int nn = n & 255;
  union { unsigned short s[8]; uint4 v; } U;
  #pragma unroll
  for (int e = 0; e < 8; ++e) U.s[e] = f2h(sp[(size_t)(kb + e) * 256 + nn]);
  *(uint4*)(dst + id) = U.v;
}

// ---------------------------------------------------------------------------
// Legacy 64x64 GEMM tile (k_prep only; plain caching, gather variants).
// LDS from smc: As 2x32x68 @0, Bs @17408, stat @34816, red @35328 -> 37376.
template <int LN, int GR>
__device__ void gemm_tile(const float* gsrc, const int* seqIdx,
                          const float* B, const float* bias, float* C,
                          const float* lns, const float* lnb,
                          int M, int K, int N, int m0, int n0, char* smc) {
  float (*As)[32][68] = (float (*)[32][68])smc;
  float (*Bs)[32][68] = (float (*)[32][68])(smc + 17408);
  float (*stat)[2]    = (float (*)[2])(smc + 34816);
  float (*red)[8]     = (float (*)[8])(smc + 35328);

  int t = threadIdx.x;
  int arow = t >> 2, akq = (t & 3) * 8;
  int mg = m0 + arow;
  int mgc = mg < M ? mg : M - 1;
  const float* Ar = (GR == 1) ? (gsrc + (size_t)seqIdx[mgc] * K)
                              : (gsrc + (size_t)bucket_of(mgc) * K);
  float mean = 0.f, rstd = 0.f;
  if (LN) {
    int lq = t & 3;
    float s = 0.f, s2 = 0.f;
    const float* p = Ar + lq * 64;
    #pragma unroll
    for (int c = 0; c < 64; c += 4) {
      float4 v = *(const float4*)(p + c);
      s  += v.x + v.y + v.z + v.w;
      s2 += v.x * v.x + v.y * v.y + v.z * v.z + v.w * v.w;
    }
    red[arow][lq] = s; red[arow][lq + 4] = s2;
    __syncthreads();
    if (lq == 0) {
      float sm = red[arow][0] + red[arow][1] + red[arow][2] + red[arow][3];
      float sq = red[arow][4] + red[arow][5] + red[arow][6] + red[arow][7];
      float m = sm * (1.f / 256.f);
      float v = sq * (1.f / 256.f) - m * m;
      stat[arow][0] = m;
      stat[arow][1] = rsqrtf(v + 1e-5f);
    }
    __syncthreads();
    mean = stat[arow][0]; rstd = stat[arow][1];
  }

  int bkr = t >> 3, bn8 = (t & 7) * 8;
  int ty = t >> 4, tx = t & 15;
  float acc[4][4] = {};
  int nk = K >> 5;

  for (int kt = 0; kt < nk; ++kt) {
    int k0 = kt << 5;
    float4 a0 = *(const float4*)(Ar + k0 + akq);
    float4 a1 = *(const float4*)(Ar + k0 + akq + 4);
    if (LN) {
      float4 ls0 = *(const float4*)(lns + k0 + akq), ls1 = *(const float4*)(lns + k0 + akq + 4);
      float4 lb0 = *(const float4*)(lnb + k0 + akq), lb1 = *(const float4*)(lnb + k0 + akq + 4);
      a0.x=(a0.x-mean)*rstd*ls0.x+lb0.x; a0.y=(a0.y-mean)*rstd*ls0.y+lb0.y;
      a0.z=(a0.z-mean)*rstd*ls0.z+lb0.z; a0.w=(a0.w-mean)*rstd*ls0.w+lb0.w;
      a1.x=(a1.x-mean)*rstd*ls1.x+lb1.x; a1.y=(a1.y-mean)*rstd*ls1.y+lb1.y;
      a1.z=(a1.z-mean)*rstd*ls1.z+lb1.z; a1.w=(a1.w-mean)*rstd*ls1.w+lb1.w;
    }
    int cur = kt & 1;
    As[cur][akq+0][arow]=a0.x; As[cur][akq+1][arow]=a0.y; As[cur][akq+2][arow]=a0.z; As[cur][akq+3][arow]=a0.w;
    As[cur][akq+4][arow]=a1.x; As[cur][akq+5][arow]=a1.y; As[cur][akq+6][arow]=a1.z; As[cur][akq+7][arow]=a1.w;
    *(float4*)&Bs[cur][bkr][bn8] = *(const float4*)(B + (size_t)(k0 + bkr) * N + n0 + bn8);
    *(float4*)&Bs[cur][bkr][bn8+4] = *(const float4*)(B + (size_t)(k0 + bkr) * N + n0 + bn8 + 4);
    __syncthreads();
    #pragma unroll 8
    for (int kk = 0; kk < 32; ++kk) {
      float4 a = *(float4*)&As[cur][kk][ty * 4];
      float4 b = *(float4*)&Bs[cur][kk][tx * 4];
      acc[0][0]=fmaf(a.x,b.x,acc[0][0]); acc[0][1]=fmaf(a.x,b.y,acc[0][1]);
      acc[0][2]=fmaf(a.x,b.z,acc[0][2]); acc[0][3]=fmaf(a.x,b.w,acc[0][3]);
      acc[1][0]=fmaf(a.y,b.x,acc[1][0]); acc[1][1]=fmaf(a.y,b.y,acc[1][1]);
      acc[1][2]=fmaf(a.y,b.z,acc[1][2]); acc[1][3]=fmaf(a.y,b.w,acc[1][3]);
      acc[2][0]=fmaf(a.z,b.x,acc[2][0]); acc[2][1]=fmaf(a.z,b.y,acc[2][1]);
      acc[2][2]=fmaf(a.z,b.z,acc[2][2]); acc[2][3]=fmaf(a.z,b.w,acc[2][3]);
      acc[3][0]=fmaf(a.w,b.x,acc[3][0]); acc[3][1]=fmaf(a.w,b.y,acc[3][1]);
      acc[3][2]=fmaf(a.w,b.z,acc[3][2]); acc[3][3]=fmaf(a.w,b.w,acc[3][3]);
    }
    __syncthreads();
  }

  #pragma unroll
  for (int u = 0; u < 4; ++u) {
    int m = m0 + ty * 4 + u;
    if (m < M) {
      int n = n0 + tx * 4;
      float4 val = make_float4(acc[u][0], acc[u][1], acc[u][2], acc[u][3]);
      if (bias) {
        float4 bv = *(const float4*)(bias + n);
        val.x += bv.x; val.y += bv.y; val.z += bv.z; val.w += bv.w;
      }
      *(float4*)(C + (size_t)m * N + n) = val;
    }
  }
}

// ---------------------------------------------------------------------------
// Prep: RB gemm + qkv layer0 + embed + abias + W1p pack + fp16 weight packs.
__global__ __launch_bounds__(256, 2) void k_prep(
    const int* __restrict__ seq, const float* __restrict__ tok_emb,
    const float* __restrict__ rp_emb,
    const float* __restrict__ wq, const float* __restrict__ wk,
    const float* __restrict__ wv, const float* __restrict__ wo,
    const float* __restrict__ ffn_w1, const float* __restrict__ ffn_w2,
    const float* __restrict__ ln1s0, const float* __restrict__ ln1b0,
    const float* __restrict__ pair_rp, const float* __restrict__ cls_w1,
    const float* __restrict__ cls_b1,
    const float* __restrict__ pair_q_w, const float* __restrict__ pair_k_w,
    float* x0, float* q0, float* k0, float* v0, float* RB,
    unsigned short* W1p, float* abias,
    unsigned short* Wop, unsigned short* W1pk, unsigned short* W2pk,
    unsigned short* Wqkvp, unsigned short* Wpairp) {
  __shared__ __align__(16) char sm[37376];
  int b = blockIdx.x, t = threadIdx.x;
  if (b < 96) {
    int m0 = (b % 24) * 64, n0 = (b / 24) * 64;
    gemm_tile<0,2>(pair_rp, nullptr, cls_w1, cls_b1, RB,
                   nullptr, nullptr, NDD, 256, 256, m0, n0, sm);
  } else if (b < 240) {
    int u = b - 96;
    int n0g = (u % 12) * 64, m0 = (u / 12) * 64;
    int bi = n0g >> 8, n0 = n0g & 255;
    const float* B = bi == 0 ? wq : (bi == 1 ? wk : wv);
    float* C = bi == 0 ? q0 : (bi == 1 ? k0 : v0);
    gemm_tile<1,1>(tok_emb, seq, B, nullptr, C,
                   ln1s0, ln1b0, LSEQ, 256, 256, m0, n0, sm);
  } else if (b < 432) {
    int row = (b - 240) * 4 + (t >> 6), c = (t & 63) * 4;
    *(float4*)(x0 + (size_t)row * DM + c) =
        *(const float4*)(tok_emb + (size_t)seq[row] * DM + c);
  } else if (b < 438) {
    int dd = (b - 432) * 256 + t;
    if (dd < NDD) {
      int bk = bucket_of(dd);
      #pragma unroll
      for (int h = 0; h < NH; ++h) abias[dd * 8 + h] = rp_emb[bk * 8 + h];
    }
  } else if (b < 502) {
    // cls_w1 pack -> fp16 fragments (consumed by k_pair3)
    int base = (b - 438) * 1024 + t * 4;
    #pragma unroll
    for (int uu = 0; uu < 4; ++uu) {
      int id = base + uu;
      int e = id & 7, lane = (id >> 3) & 63, g = (id >> 9) & 15, kc = id >> 13;
      int kg = kc * 32 + (lane >> 4) * 8 + e;
      int n  = g * 16 + (lane & 15);
      W1p[id] = f2h(cls_w1[(size_t)kg * 256 + n]);
    }
  } else {
    // fp16 MFMA weight packing: 3136 blocks x 2048 elems
    int u = (b - 502) * 2048 + t * 8;
    if (u < 524288) {                       // wo: 8 x [256][256], G=16
      int layer = u >> 16, id = u & 65535;
      pack8h(Wop + ((size_t)layer << 16), id, wo + ((size_t)layer << 16), 256, 16);
    } else if (u < 2621440) {               // ffn_w1: 8 x [256][1024], G=64
      int v2 = u - 524288; int layer = v2 >> 18, id = v2 & 262143;
      pack8h(W1pk + ((size_t)layer << 18), id, ffn_w1 + ((size_t)layer << 18), 1024, 64);
    } else if (u < 4718592) {               // ffn_w2: 8 x [1024][256], G=16
      int v2 = u - 2621440; int layer = v2 >> 18, id = v2 & 262143;
      pack8h(W2pk + ((size_t)layer << 18), id, ffn_w2 + ((size_t)layer << 18), 256, 16);
    } else if (u < 6291456) {               // qkv concat: 8 x [256][768], G=48
      int v2 = u - 4718592; int layer = v2 / 196608, id = v2 - layer * 196608;
      pack8h_cat(Wqkvp + (size_t)layer * 196608, id,
                 wq + ((size_t)layer << 16), wk + ((size_t)layer << 16),
                 wv + ((size_t)layer << 16), 48);
    } else {                                // pair q/k concat: [256][512], G=32
      int id = u - 6291456;
      pack8h_cat(Wpairp, id, pair_q_w, pair_k_w, pair_k_w, 32);
    }
  }
}

// ---------------------------------------------------------------------------
// Attention (validated round 7): 16 q-rows x 1 head per block.
#define ATTN_SMEM 72960

__global__ __launch_bounds__(256, 2) void k_attn2(
    const float* __restrict__ q, const float* __restrict__ k,
    const float* __restrict__ v, const float* __restrict__ abias,
    float* __restrict__ o) {
  extern __shared__ char sm[];
  float* S  = (float*)sm;
  float* KV = (float*)(sm + 49664);
  float* QS = (float*)(sm + 66560);
  float* BS = (float*)(sm + 68672);
  float (*red)[16] = (float (*)[16])(sm + 71808);
  float* mrow = (float*)(sm + 72832);
  float* linv = (float*)(sm + 72896);

  int i0 = blockIdx.x * 16, h = blockIdx.y, hc = h * DK;
  int t = threadIdx.x;

  for (int u = t; u < 783; u += 256)
    BS[u] = abias[(size_t)(i0 + u) * 8 + h];
  {
    int r = t >> 4, c = t & 15;
    const float inv = 0.17677669529663687f;   // 1/sqrt(32)
    QS[r * 33 + c]      = q[(size_t)(i0 + r) * DM + hc + c] * inv;
    QS[r * 33 + c + 16] = q[(size_t)(i0 + r) * DM + hc + c + 16] * inv;
  }

  int kx = t & 31, ry = t >> 5;
  int key = t >> 1, half = t & 1;

  for (int cc = 0; cc < 6; ++cc) {
    const float* kp = k + (size_t)(cc * 128 + key) * DM + hc + half * 16;
    float4 L0 = *(const float4*)(kp);
    float4 L1 = *(const float4*)(kp + 4);
    float4 L2 = *(const float4*)(kp + 8);
    float4 L3 = *(const float4*)(kp + 12);
    __syncthreads();
    int cb = half * 16;
    KV[(cb+ 0)*132+key]=L0.x; KV[(cb+ 1)*132+key]=L0.y; KV[(cb+ 2)*132+key]=L0.z; KV[(cb+ 3)*132+key]=L0.w;
    KV[(cb+ 4)*132+key]=L1.x; KV[(cb+ 5)*132+key]=L1.y; KV[(cb+ 6)*132+key]=L1.z; KV[(cb+ 7)*132+key]=L1.w;
    KV[(cb+ 8)*132+key]=L2.x; KV[(cb+ 9)*132+key]=L2.y; KV[(cb+10)*132+key]=L2.z; KV[(cb+11)*132+key]=L2.w;
    KV[(cb+12)*132+key]=L3.x; KV[(cb+13)*132+key]=L3.y; KV[(cb+14)*132+key]=L3.z; KV[(cb+15)*132+key]=L3.w;
    __syncthreads();

    float s0x=0,s0y=0,s0z=0,s0w=0, s1x=0,s1y=0,s1z=0,s1w=0;
    #pragma unroll
    for (int kk = 0; kk < 32; ++kk) {
      float q0 = QS[(ry*2    )*33 + kk];
      float q1 = QS[(ry*2 + 1)*33 + kk];
      float4 kv4 = *(const float4*)&KV[kk*132 + kx*4];
      s0x = fmaf(q0, kv4.x, s0x); s0y = fmaf(q0, kv4.y, s0y);
      s0z = fmaf(q0, kv4.z, s0z); s0w = fmaf(q0, kv4.w, s0w);
      s1x = fmaf(q1, kv4.x, s1x); s1y = fmaf(q1, kv4.y, s1y);
      s1z = fmaf(q1, kv4.z, s1z); s1w = fmaf(q1, kv4.w, s1w);
    }
    int jb = cc * 128 + kx * 4;
    int r0 = ry * 2, r1 = r0 + 1;
    S[r0*776 + jb+0] = s0x + BS[r0 + 767 - (jb+0)];
    S[r0*776 + jb+1] = s0y + BS[r0 + 767 - (jb+1)];
    S[r0*776 + jb+2] = s0z + BS[r0 + 767 - (jb+2)];
    S[r0*776 + jb+3] = s0w + BS[r0 + 767 - (jb+3)];
    S[r1*776 + jb+0] = s1x + BS[r1 + 767 - (jb+0)];
    S[r1*776 + jb+1] = s1y + BS[r1 + 767 - (jb+1)];
    S[r1*776 + jb+2] = s1z + BS[r1 + 767 - (jb+2)];
    S[r1*776 + jb+3] = s1w + BS[r1 + 767 - (jb+3)];
  }
  __syncthreads();

  {
    int ti = t >> 4, tj = t & 15;
    float mx = -1e30f;
    for (int jc = 0; jc < 48; ++jc)
      mx = fmaxf(mx, S[ti*776 + jc*16 + tj]);
    red[ti][tj] = mx;
    __syncthreads();
    if (tj == 0) {
      float m2 = red[ti][0];
      #pragma unroll
      for (int u = 1; u < 16; ++u) m2 = fmaxf(m2, red[ti][u]);
      mrow[ti] = m2;
    }
    __syncthreads();
    float m2 = mrow[ti];
    float sum = 0.f;
    for (int jc = 0; jc < 48; ++jc) {
      int j = jc*16 + tj;
      float e = __expf(S[ti*776 + j] - m2);
      S[ti*776 + j] = e;
      sum += e;
    }
    red[ti][tj] = sum;
    __syncthreads();
    if (tj == 0) {
      float s2 = 0.f;
      #pragma unroll
      for (int u = 0; u < 16; ++u) s2 += red[ti][u];
      linv[ti] = 1.f / s2;
    }
  }

  int cp = t & 15, jg = t >> 4;
  int c0 = cp * 2, c1 = c0 + 1;
  float oc0[16] = {}, oc1[16] = {};
  for (int cc = 0; cc < 6; ++cc) {
    const float* vp = v + (size_t)(cc * 128 + key) * DM + hc + half * 16;
    float4 L0 = *(const float4*)(vp);
    float4 L1 = *(const float4*)(vp + 4);
    float4 L2 = *(const float4*)(vp + 8);
    float4 L3 = *(const float4*)(vp + 12);
    __syncthreads();
    int cb = half * 16;
    KV[(cb+ 0)*132+key]=L0.x; KV[(cb+ 1)*132+key]=L0.y; KV[(cb+ 2)*132+key]=L0.z; KV[(cb+ 3)*132+key]=L0.w;
    KV[(cb+ 4)*132+key]=L1.x; KV[(cb+ 5)*132+key]=L1.y; KV[(cb+ 6)*132+key]=L1.z; KV[(cb+ 7)*132+key]=L1.w;
    KV[(cb+ 8)*132+key]=L2.x; KV[(cb+ 9)*132+key]=L2.y; KV[(cb+10)*132+key]=L2.z; KV[(cb+11)*132+key]=L2.w;
    KV[(cb+12)*132+key]=L3.x; KV[(cb+13)*132+key]=L3.y; KV[(cb+14)*132+key]=L3.z; KV[(cb+15)*132+key]=L3.w;
    __syncthreads();

    #pragma unroll
    for (int jj2 = 0; jj2 < 2; ++jj2) {
      int jb = jg * 8 + jj2 * 4;
      float4 vA = *(const float4*)&KV[c0*132 + jb];
      float4 vB = *(const float4*)&KV[c1*132 + jb];
      #pragma unroll
      for (int r = 0; r < 16; ++r) {
        float4 sv = *(const float4*)&S[r*776 + cc*128 + jb];
        oc0[r] += sv.x*vA.x + sv.y*vA.y + sv.z*vA.z + sv.w*vA.w;
        oc1[r] += sv.x*vB.x + sv.y*vB.y + sv.z*vB.z + sv.w*vB.w;
      }
    }
  }

  #pragma unroll
  for (int h2 = 0; h2 < 2; ++h2) {
    __syncthreads();
    #pragma unroll
    for (int r = 0; r < 8; ++r) {
      KV[(jg*8 + r)*32 + c0] = oc0[h2*8 + r];
      KV[(jg*8 + r)*32 + c1] = oc1[h2*8 + r];
    }
    __syncthreads();
    int r = t >> 5, c = t & 31;
    float s = 0.f;
    #pragma unroll
    for (int jgg = 0; jgg < 16; ++jgg) s += KV[(jgg*8 + r)*32 + c];
    o[(size_t)(i0 + h2*8 + r) * DM + hc + c] = s * linv[h2*8 + r];
  }
}

// ---------------------------------------------------------------------------
// Layer tail, wave-maximized (validated round 7): 1 16x16 MFMA tile per wave.

// k_wo: X1 = xin + O@Wo. grid (48,4) x 256thr; wave w -> g = by*4+w.
__global__ __launch_bounds__(256, 2) void k_wo(
    const float* __restrict__ o, const float* __restrict__ xin,
    const unsigned short* __restrict__ wop, float* __restrict__ x1) {
  __shared__ __align__(16) _Float16 Ab[16][264];
  int t = threadIdx.x;
  int i0 = blockIdx.x * 16;
  int by = blockIdx.y;
  int w = t >> 6, l = t & 63;
  int lr = l & 15, lq = l >> 4;

  {
    int r = t >> 4, j = t & 15;
    #pragma unroll
    for (int q = 0; q < 4; ++q) {
      int c = j * 4 + q * 64;
      float4 v = *(const float4*)(o + (size_t)(i0 + r) * DM + c);
      union { _Float16 h[4]; uint2 u; } cv;
      cv.h[0] = (_Float16)v.x; cv.h[1] = (_Float16)v.y;
      cv.h[2] = (_Float16)v.z; cv.h[3] = (_Float16)v.w;
      *(uint2*)&Ab[r][c] = cv.u;
    }
  }
  __syncthreads();

  f16x8 af[8];
  #pragma unroll
  for (int kc = 0; kc < 8; ++kc)
    af[kc] = *(const f16x8*)&Ab[lr][kc * 32 + lq * 8];

  int g = by * 4 + w;
  const unsigned short* wp = wop + (size_t)l * 8;
  f32x4 ac = {0.f, 0.f, 0.f, 0.f};
  #pragma unroll
  for (int kc = 0; kc < 8; ++kc) {
    f16x8 bb = *(const f16x8*)(wp + ((kc * 16 + g) << 9));
    ac = __builtin_amdgcn_mfma_f32_16x16x32_f16(af[kc], bb, ac, 0, 0, 0);
  }
  int n = g * 16 + lr;
  #pragma unroll
  for (int r = 0; r < 4; ++r) {
    int row = i0 + lq * 4 + r;
    x1[(size_t)row * DM + n] = xin[(size_t)row * DM + n] + ac[r];
  }
}

// k_ffn1: LN2(x1) -> ffn1 chunk + gelu -> Fg. grid (48,16); wave -> g = by*4+w.
__global__ __launch_bounds__(256, 2) void k_ffn1(
    const float* __restrict__ x1,
    const float* __restrict__ ln2s, const float* __restrict__ ln2b,
    const unsigned short* __restrict__ w1p, const float* __restrict__ fb1,
    unsigned short* __restrict__ Fg) {
  __shared__ __align__(16) _Float16 Ab[16][264];
  int t = threadIdx.x;
  int i0 = blockIdx.x * 16;
  int by = blockIdx.y;
  int w = t >> 6, l = t & 63;
  int lr = l & 15, lq = l >> 4;

  // LN2 from global x1 (16 threads/row, shuffle reduce) -> Ab fp16
  {
    int r = t >> 4, j = t & 15;
    int c0 = j * 16;
    const float* xp = x1 + (size_t)(i0 + r) * DM + c0;
    float xv[16]; float s1 = 0.f, s2 = 0.f;
    #pragma unroll
    for (int u = 0; u < 16; u += 4) {
      float4 v = *(const float4*)(xp + u);
      xv[u] = v.x; xv[u+1] = v.y; xv[u+2] = v.z; xv[u+3] = v.w;
      s1 += v.x + v.y + v.z + v.w;
      s2 += v.x*v.x + v.y*v.y + v.z*v.z + v.w*v.w;
    }
    #pragma unroll
    for (int m = 1; m < 16; m <<= 1) {
      s1 += __shfl_xor(s1, m);
      s2 += __shfl_xor(s2, m);
    }
    float mean = s1 * (1.f / 256.f);
    float var  = s2 * (1.f / 256.f) - mean * mean;
    float rs = rsqrtf(var + 1e-5f);
    #pragma unroll
    for (int p = 0; p < 4; ++p) {
      union { _Float16 h[4]; uint2 u; } cv;
      #pragma unroll
      for (int e = 0; e < 4; ++e) {
        int c = c0 + p * 4 + e;
        cv.h[e] = (_Float16)((xv[p * 4 + e] - mean) * rs * ln2s[c] + ln2b[c]);
      }
      *(uint2*)&Ab[r][c0 + p * 4] = cv.u;
    }
  }
  __syncthreads();

  f16x8 af[8];
  #pragma unroll
  for (int kc = 0; kc < 8; ++kc)
    af[kc] = *(const f16x8*)&Ab[lr][kc * 32 + lq * 8];

  int g = by * 4 + w;
  const unsigned short* wp = w1p + (size_t)l * 8;
  f32x4 ac = {0.f, 0.f, 0.f, 0.f};
  #pragma unroll
  for (int kc = 0; kc < 8; ++kc) {
    f16x8 bb = *(const f16x8*)(wp + ((kc * 64 + g) << 9));
    ac = __builtin_amdgcn_mfma_f32_16x16x32_f16(af[kc], bb, ac, 0, 0, 0);
  }
  int n = g * 16 + lr;
  float b1 = fb1[n];
  #pragma unroll
  for (int r = 0; r < 4; ++r) {
    float v = ac[r] + b1;
    v = 0.5f * v * (1.f + erff(v * 0.70710678118654752f));
    Fg[(size_t)(i0 + lq * 4 + r) * DFF + n] = f2h(v);
  }
}

// k_ffn2: X2 = X1 + F@W2 + b2. grid (48,16); block = one 16x16 tile (g = by),
// 4 waves K-split K=1024 (256 each), LDS partial reduce, wave 0 writes.
__global__ __launch_bounds__(256, 2) void k_ffn2(
    const unsigned short* __restrict__ Fg, const float* __restrict__ x1,
    const unsigned short* __restrict__ w2p, const float* __restrict__ fb2,
    float* __restrict__ x2) {
  __shared__ __align__(16) _Float16 Fs[16][1032];
  __shared__ float part[3][16][17];
  int t = threadIdx.x;
  int i0 = blockIdx.x * 16;
  int g = blockIdx.y;
  int w = t >> 6, l = t & 63;
  int lr = l & 15, lq = l >> 4;

  {
    int r = t >> 4, j = t & 15;
    #pragma unroll
    for (int q = 0; q < 8; ++q) {
      int c = j * 8 + q * 128;
      *(uint4*)&Fs[r][c] = *(const uint4*)(Fg + (size_t)(i0 + r) * DFF + c);
    }
  }
  __syncthreads();

  const unsigned short* wp = w2p + (size_t)l * 8;
  f32x4 ac = {0.f, 0.f, 0.f, 0.f};
  #pragma unroll
  for (int k8 = 0; k8 < 8; ++k8) {
    int kc = w * 8 + k8;
    f16x8 fa = *(const f16x8*)&Fs[lr][kc * 32 + lq * 8];
    f16x8 bb = *(const f16x8*)(wp + ((kc * 16 + g) << 9));
    ac = __builtin_amdgcn_mfma_f32_16x16x32_f16(fa, bb, ac, 0, 0, 0);
  }
  if (w > 0) {
    #pragma unroll
    for (int r = 0; r < 4; ++r)
      part[w - 1][lq * 4 + r][lr] = ac[r];
  }
  __syncthreads();
  if (w == 0) {
    int n = g * 16 + lr;
    float b2v = fb2[n];
    #pragma unroll
    for (int r = 0; r < 4; ++r) {
      int rr = lq * 4 + r;
      int row = i0 + rr;
      float s = ac[r] + part[0][rr][lr] + part[1][rr][lr] + part[2][rr][lr];
      x2[(size_t)row * DM + n] = x1[(size_t)row * DM + n] + s + b2v;
    }
  }
}

// k_t3: LN1next/LNf + qkv chunk (or pair projection). 1 g per wave.
// grid (48,12) for qkv (G=48), (48,8) for pair (G=32).
template <int LAST>
__global__ __launch_bounds__(256, 2) void k_t3(
    const float* __restrict__ x2,
    const float* __restrict__ lns, const float* __restrict__ lnb,
    const unsigned short* __restrict__ wnp,
    const float* __restrict__ nb0, const float* __restrict__ nb1,
    float* __restrict__ qo, float* __restrict__ ko, float* __restrict__ vo) {
  __shared__ __align__(16) _Float16 Ab[16][264];
  int t = threadIdx.x;
  int i0 = blockIdx.x * 16;
  int by = blockIdx.y;
  int w = t >> 6, l = t & 63;
  int lr = l & 15, lq = l >> 4;

  {
    int r = t >> 4, j = t & 15;
    int c0 = j * 16;
    const float* xp = x2 + (size_t)(i0 + r) * DM + c0;
    float xv[16]; float s1 = 0.f, s2 = 0.f;
    #pragma unroll
    for (int u = 0; u < 16; u += 4) {
      float4 v = *(const float4*)(xp + u);
      xv[u] = v.x; xv[u+1] = v.y; xv[u+2] = v.z; xv[u+3] = v.w;
      s1 += v.x + v.y + v.z + v.w;
      s2 += v.x*v.x + v.y*v.y + v.z*v.z + v.w*v.w;
    }
    #pragma unroll
    for (int m = 1; m < 16; m <<= 1) {
      s1 += __shfl_xor(s1, m);
      s2 += __shfl_xor(s2, m);
    }
    float mean = s1 * (1.f / 256.f);
    float var  = s2 * (1.f / 256.f) - mean * mean;
    float rs = rsqrtf(var + 1e-5f);
    #pragma unroll
    for (int p = 0; p < 4; ++p) {
      union { _Float16 h[4]; uint2 u; } cv;
      #pragma unroll
      for (int e = 0; e < 4; ++e) {
        int c = c0 + p * 4 + e;
        cv.h[e] = (_Float16)((xv[p * 4 + e] - mean) * rs * lns[c] + lnb[c]);
      }
      *(uint2*)&Ab[r][c0 + p * 4] = cv.u;
    }
  }
  __syncthreads();

  f16x8 af[8];
  #pragma unroll
  for (int kc = 0; kc < 8; ++kc)
    af[kc] = *(const f16x8*)&Ab[lr][kc * 32 + lq * 8];

  const unsigned short* wp = wnp + (size_t)l * 8;
  int g = by * 4 + w;
  if (!LAST) {
    f32x4 ac = {0.f, 0.f, 0.f, 0.f};
    #pragma unroll
    for (int kc = 0; kc < 8; ++kc) {
      f16x8 bb = *(const f16x8*)(wp + ((kc * 48 + g) << 9));
      ac = __builtin_amdgcn_mfma_f32_16x16x32_f16(af[kc], bb, ac, 0, 0, 0);
    }
    int n = g * 16 + lr;
    float* dst = n < 256 ? qo : (n < 512 ? ko : vo);
    int nn = n & 255;
    #pragma unroll
    for (int r = 0; r < 4; ++r)
      dst[(size_t)(i0 + lq * 4 + r) * DM + nn] = ac[r];
  } else {
    f32x4 ac = {0.f, 0.f, 0.f, 0.f};
    #pragma unroll
    for (int kc = 0; kc < 8; ++kc) {
      f16x8 bb = *(const f16x8*)(wp + ((kc * 32 + g) << 9));
      ac = __builtin_amdgcn_mfma_f32_16x16x32_f16(af[kc], bb, ac, 0, 0, 0);
    }
    int n = g * 16 + lr;
    float* dst = n < 256 ? qo : ko;
    const float* bias = n < 256 ? nb0 : nb1;
    int nn = n & 255;
    float bv = bias[nn];
    #pragma unroll
    for (int r = 0; r < 4; ++r)
      dst[(size_t)(i0 + lq * 4 + r) * DM + nn] = ac[r] + bv;
  }
}

// ---------------------------------------------------------------------------
// Fused pair head v5 (validated round 12/16, session best): fp32 RB_s LDS
// staging, fp16 q/k staging, pk_mul + f16 MFMA, disjoint-store epilogue
// racc2[nwv][r][2] + final 2-way add (no atomics).
__global__ __launch_bounds__(256, 2) void k_pair3(
    const float* __restrict__ pq, const float* __restrict__ pk,
    const unsigned short* __restrict__ W1p, const float* __restrict__ RB,
    const float* __restrict__ w2, const float* __restrict__ b2,
    float* __restrict__ out) {
  __shared__ __align__(16) _Float16 qsh[4][264];
  __shared__ __align__(16) _Float16 ksh[32][264];
  __shared__ __align__(16) float    RB_s[35][260];
  __shared__ float racc2[2][128][2];

  int t = threadIdx.x;
  int j0 = blockIdx.x * 32;
  int i0 = blockIdx.y * 4;
  int w = t >> 6, l = t & 63;
  int q4 = l >> 4, l15 = l & 15;
  int mwv = w & 1, nwv = w >> 1;

  // stage q (4x256) + k (32x256) as fp16, RB tile as fp32
  {
    if (t < 128) {
      int kr = t >> 5, c8 = (t & 31) * 8;
      const float* sp = pq + (size_t)(i0 + kr) * DM + c8;
      float4 a = *(const float4*)sp, b = *(const float4*)(sp + 4);
      f16x8 h;
      h[0]=(_Float16)a.x; h[1]=(_Float16)a.y; h[2]=(_Float16)a.z; h[3]=(_Float16)a.w;
      h[4]=(_Float16)b.x; h[5]=(_Float16)b.y; h[6]=(_Float16)b.z; h[7]=(_Float16)b.w;
      *(f16x8*)&qsh[kr][c8] = h;
    }
    #pragma unroll
    for (int r8 = 0; r8 < 4; ++r8) {
      int idx = t + r8 * 256;
      int kr = idx >> 5, c8 = (idx & 31) * 8;
      const float* sp = pk + (size_t)(j0 + kr) * DM + c8;
      float4 a = *(const float4*)sp, b = *(const float4*)(sp + 4);
      f16x8 h;
      h[0]=(_Float16)a.x; h[1]=(_Float16)a.y; h[2]=(_Float16)a.z; h[3]=(_Float16)a.w;
      h[4]=(_Float16)b.x; h[5]=(_Float16)b.y; h[6]=(_Float16)b.z; h[7]=(_Float16)b.w;
      *(f16x8*)&ksh[kr][c8] = h;
    }
    int ddmin = i0 - j0 + 736;
    for (int idx = t; idx < 35 * 64; idx += 256) {
      int lc = idx >> 6, c4b = (idx & 63) * 4;
      *(float4*)&RB_s[lc][c4b] =
          *(const float4*)(RB + (size_t)(ddmin + lc) * 256 + c4b);
    }
  }
  __syncthreads();

  const unsigned short* Bp = W1p + (size_t)(nwv * 8) * 512 + (size_t)l * 8;

  f32x4 acc[4][8];
  #pragma unroll
  for (int aa = 0; aa < 4; ++aa)
    #pragma unroll
    for (int bb = 0; bb < 8; ++bb) acc[aa][bb] = (f32x4){0.f, 0.f, 0.f, 0.f};

  f16x8 bcur[8];
  #pragma unroll
  for (int nt = 0; nt < 8; ++nt) bcur[nt] = *(const f16x8*)(Bp + nt * 512);

  for (int kc = 0; kc < 8; ++kc) {
    f16x8 bnxt[8];
    if (kc < 7) {
      const unsigned short* bbn = Bp + (size_t)(kc + 1) * 8192;
      #pragma unroll
      for (int nt = 0; nt < 8; ++nt) bnxt[nt] = *(const f16x8*)(bbn + nt * 512);
    }
    int c = kc * 32 + q4 * 8;
    f16x8 qa = *(const f16x8*)&qsh[mwv * 2][c];
    f16x8 qb = *(const f16x8*)&qsh[mwv * 2 + 1][c];
    f16x8 ka = *(const f16x8*)&ksh[l15][c];
    f16x8 kb = *(const f16x8*)&ksh[16 + l15][c];

    f16x8 af0 = qa * ka;   // v_pk_mul_f16 x4
    f16x8 af1 = qa * kb;
    f16x8 af2 = qb * ka;
    f16x8 af3 = qb * kb;

    #pragma unroll
    for (int nt = 0; nt < 8; ++nt) {
      acc[0][nt] = __builtin_amdgcn_mfma_f32_16x16x32_f16(af0, bcur[nt], acc[0][nt], 0, 0, 0);
      acc[1][nt] = __builtin_amdgcn_mfma_f32_16x16x32_f16(af1, bcur[nt], acc[1][nt], 0, 0, 0);
      acc[2][nt] = __builtin_amdgcn_mfma_f32_16x16x32_f16(af2, bcur[nt], acc[2][nt], 0, 0, 0);
      acc[3][nt] = __builtin_amdgcn_mfma_f32_16x16x32_f16(af3, bcur[nt], acc[3][nt], 0, 0, 0);
    }
    if (kc < 7) {
      #pragma unroll
      for (int nt = 0; nt < 8; ++nt) bcur[nt] = bnxt[nt];
    }
  }

  float w20[8], w21[8];
  #pragma unroll
  for (int nt = 0; nt < 8; ++nt) {
    int n = nwv * 128 + nt * 16 + l15;
    w20[nt] = w2[n * 2];
    w21[nt] = w2[n * 2 + 1];
  }
  #pragma unroll
  for (int mt = 0; mt < 4; ++mt) {
    #pragma unroll
    for (int reg = 0; reg < 4; ++reg) {
      int r = mwv * 64 + mt * 16 + q4 * 4 + reg;
      int lc = (r >> 5) - (r & 31) + 31;
      float o0 = 0.f, o1 = 0.f;
      #pragma unroll
      for (int nt = 0; nt < 8; ++nt) {
        int n = nwv * 128 + nt * 16 + l15;
        float T = acc[mt][nt][reg] + RB_s[lc][n];
        T = fmaxf(T, 0.f);
        o0 = fmaf(T, w20[nt], o0);
        o1 = fmaf(T, w21[nt], o1);
      }
      #pragma unroll
      for (int s = 1; s < 16; s <<= 1) {
        o0 += __shfl_xor(o0, s);
        o1 += __shfl_xor(o1, s);
      }
      if (l15 == 0) {
        racc2[nwv][r][0] = o0;
        racc2[nwv][r][1] = o1;
      }
    }
  }
  __syncthreads();
  {
    int r = t >> 1, oo = t & 1;
    out[((size_t)(i0 + (r >> 5)) * LSEQ + (j0 + (r & 31))) * 2 + oo] =
        racc2[0][r][oo] + racc2[1][r][oo] + b2[oo];
  }
}

// ---------------------------------------------------------------------------
extern "C" void kernel_launch(void* const* d_in, const int* in_sizes, int n_in,
                              void* d_out, int out_size, void* d_ws, size_t ws_size,
                              hipStream_t stream) {
  const int*   seq      = (const int*)  d_in[0];
  const float* tok_emb  = (const float*)d_in[1];
  const float* rp_emb   = (const float*)d_in[2];
  const float* wq       = (const float*)d_in[3];
  const float* wk       = (const float*)d_in[4];
  const float* wv       = (const float*)d_in[5];
  const float* wo       = (const float*)d_in[6];
  const float* ln1_s    = (const float*)d_in[7];
  const float* ln1_b    = (const float*)d_in[8];
  const float* ln2_s    = (const float*)d_in[9];
  const float* ln2_b    = (const float*)d_in[10];
  const float* ffn_w1   = (const float*)d_in[11];
  const float* ffn_b1   = (const float*)d_in[12];
  const float* ffn_w2   = (const float*)d_in[13];
  const float* ffn_b2   = (const float*)d_in[14];
  const float* lnf_s    = (const float*)d_in[15];
  const float* lnf_b    = (const float*)d_in[16];
  const float* pair_q_w = (const float*)d_in[17];
  const float* pair_q_b = (const float*)d_in[18];
  const float* pair_k_w = (const float*)d_in[19];
  const float* pair_k_b = (const float*)d_in[20];
  const float* pair_rp  = (const float*)d_in[21];
  const float* cls_w1   = (const float*)d_in[22];
  const float* cls_b1   = (const float*)d_in[23];
  const float* cls_w2   = (const float*)d_in[24];
  const float* cls_b2   = (const float*)d_in[25];
  float* out = (float*)d_out;

  char* ws = (char*)d_ws;
  float* xb0 = (float*)(ws + 0);
  float* xb1 = (float*)(ws + 786432);
  float* qb[2] = { (float*)(ws + 1572864), (float*)(ws + 3932160) };
  float* kb[2] = { (float*)(ws + 2359296), (float*)(ws + 4718592) };
  float* vb[2] = { (float*)(ws + 3145728), (float*)(ws + 5505024) };
  float* o   = (float*)(ws + 6291456);
  float* pq  = (float*)(ws + 7077888);
  float* pk  = (float*)(ws + 7864320);
  float* RB  = (float*)(ws + 8650752);
  unsigned short* W1p = (unsigned short*)(ws + 10223616);
  float* abias = (float*)(ws + 10354688);
  // packed fp16 MFMA weights
  unsigned short* Wop    = (unsigned short*)(ws + 10403840);  // 8 x 65536  x2B
  unsigned short* W1pk   = (unsigned short*)(ws + 11452416);  // 8 x 262144 x2B
  unsigned short* W2pk   = (unsigned short*)(ws + 15646720);  // 8 x 262144 x2B
  unsigned short* Wqkvp  = (unsigned short*)(ws + 19841024);  // 8 x 196608 x2B
  unsigned short* Wpairp = (unsigned short*)(ws + 22986752);  // 131072 x2B
  unsigned short* Fg     = (unsigned short*)(ws + 23248896);  // 768x1024 fp16
  float* x1buf           = (float*)(ws + 24821760);           // 768x256 f32

  (void)in_sizes; (void)n_in; (void)out_size; (void)ws_size;

  hipFuncSetAttribute(reinterpret_cast<const void*>(k_attn2),
                      hipFuncAttributeMaxDynamicSharedMemorySize, ATTN_SMEM);

  k_prep<<<3638, 256, 0, stream>>>(seq, tok_emb, rp_emb, wq, wk, wv, wo,
                                   ffn_w1, ffn_w2, ln1_s, ln1_b,
                                   pair_rp, cls_w1, cls_b1, pair_q_w, pair_k_w,
                                   xb0, qb[0], kb[0], vb[0], RB, W1p, abias,
                                   Wop, W1pk, W2pk, Wqkvp, Wpairp);

  for (int l = 0; l < NLAYER; ++l) {
    int pi = l & 1, po = pi ^ 1;
    float* xin  = (l & 1) ? xb1 : xb0;
    float* xout = (l & 1) ? xb0 : xb1;

    k_attn2<<<dim3(48, 8), 256, ATTN_SMEM, stream>>>(qb[pi], kb[pi], vb[pi], abias, o);

    k_wo<<<dim3(48, 4), 256, 0, stream>>>(o, xin, Wop + ((size_t)l << 16), x1buf);

    k_ffn1<<<dim3(48, 16), 256, 0, stream>>>(
        x1buf, ln2_s + l * DM, ln2_b + l * DM,
        W1pk + ((size_t)l << 18), ffn_b1 + (size_t)l * DFF, Fg);

    k_ffn2<<<dim3(48, 16), 256, 0, stream>>>(
        Fg, x1buf, W2pk + ((size_t)l << 18), ffn_b2 + (size_t)l * DM, xout);

    if (l < NLAYER - 1) {
      k_t3<0><<<dim3(48, 12), 256, 0, stream>>>(
          xout, ln1_s + (l + 1) * DM, ln1_b + (l + 1) * DM,
          Wqkvp + (size_t)(l + 1) * 196608, nullptr, nullptr,
          qb[po], kb[po], vb[po]);
    } else {
      k_t3<1><<<dim3(48, 8), 256, 0, stream>>>(
          xout, lnf_s, lnf_b, Wpairp, pair_q_b, pair_k_b,
          pq, pk, nullptr);
    }
  }

  k_pair3<<<dim3(24, 192), 256, 0, stream>>>(pq, pk, W1p, RB, cls_w2, cls_b2, out);
}